// Round 1
// baseline (1698.703 us; speedup 1.0000x reference)
//
#include <hip/hip_runtime.h>
#include <math.h>

// ---------------------------------------------------------------------------
// MultiGraphClassifier on MI355X.
// Pipeline: 2x GraphConv per graph + cross-graph fusion + tiny head.
// Strategy: CSR build per call (counting sort), gather-side aggregation
// (no fp32 atomics on feature data), fp32 LDS-tiled GEMMs with fused
// degree-scale / bias / fusion-add epilogues.
// Note: softmax over a length-1 axis == 1.0, so emb = norm(a) + norm(f);
// W_attn / b_attn are mathematically dead.
// ---------------------------------------------------------------------------

__global__ void count_kernel(const int* __restrict__ src, const int* __restrict__ dst,
                             int* __restrict__ cnt_out, int* __restrict__ cnt_in, int E) {
  int e = blockIdx.x * blockDim.x + threadIdx.x;
  if (e < E) {
    atomicAdd(&cnt_out[src[e]], 1);
    atomicAdd(&cnt_in[dst[e]], 1);
  }
}

__global__ void isr_kernel(const int* __restrict__ cnt, float* __restrict__ isr, int n) {
  int i = blockIdx.x * blockDim.x + threadIdx.x;
  if (i < n) {
    int c = cnt[i];
    if (c < 1) c = 1;  // clip(deg, 1.0)
    isr[i] = 1.0f / sqrtf((float)c);
  }
}

// Exclusive prefix sum over n counts (n <= ~100k), single block of 1024.
// Also writes cursor[] (copy of offsets) for the scatter pass and offs[n]=total.
__global__ __launch_bounds__(1024) void scan_kernel(const int* __restrict__ cnt,
                                                    int* __restrict__ offs,
                                                    int* __restrict__ cursor, int n) {
  __shared__ int part[1024];
  int t = threadIdx.x;
  int chunk = (n + 1023) >> 10;
  int start = t * chunk;
  int end = start + chunk;
  if (end > n) end = n;
  int s = 0;
  for (int i = start; i < end; ++i) s += cnt[i];
  part[t] = s;
  __syncthreads();
  for (int off = 1; off < 1024; off <<= 1) {
    int v = (t >= off) ? part[t - off] : 0;
    __syncthreads();
    part[t] += v;
    __syncthreads();
  }
  int run = part[t] - s;  // exclusive prefix for this thread's range
  for (int i = start; i < end; ++i) {
    offs[i] = run;
    cursor[i] = run;
    run += cnt[i];
  }
  if (start < n && end == n) offs[n] = run;
}

__global__ void csr_scatter_kernel(const int* __restrict__ src, const int* __restrict__ dst,
                                   int* __restrict__ cursor, int* __restrict__ csr, int E) {
  int e = blockIdx.x * blockDim.x + threadIdx.x;
  if (e < E) {
    int p = atomicAdd(&cursor[dst[e]], 1);
    csr[p] = src[e];
  }
}

// C[M,N] = (A[M,K] (+ add_scale*add_vec[K])) @ B[K,N]  * rowscale[M]?  + bias[N]?
// Requires: N % 64 == 0, K % 32 == 0. 64x64 block tile, 4x4 per thread.
__global__ __launch_bounds__(256) void gemm_kernel(
    const float* __restrict__ A, const float* __restrict__ B, float* __restrict__ C,
    int M, int N, int K,
    const float* __restrict__ add_vec, float add_scale,
    const float* __restrict__ rowscale, const float* __restrict__ bias) {
  __shared__ float As[32][68];  // [k][m], +4 pad keeps float4 alignment, no conflicts
  __shared__ float Bs[32][68];  // [k][n]
  const int m0 = blockIdx.x * 64;
  const int n0 = blockIdx.y * 64;
  const int tid = threadIdx.x;
  const int tx = tid & 15, ty = tid >> 4;
  const int ka = tid & 31, ra0 = tid >> 5;  // A-tile loader coords
  const int nb = tid & 63, kb0 = tid >> 6;  // B-tile loader coords
  float acc[4][4] = {};
  for (int k0 = 0; k0 < K; k0 += 32) {
#pragma unroll
    for (int i = 0; i < 8; ++i) {
      int m = m0 + ra0 + i * 8;
      float v = 0.f;
      if (m < M) {
        v = A[(size_t)m * K + (k0 + ka)];
        if (add_vec) v += add_scale * add_vec[k0 + ka];
      }
      As[ka][ra0 + i * 8] = v;
    }
#pragma unroll
    for (int i = 0; i < 8; ++i) {
      Bs[kb0 + i * 4][nb] = B[(size_t)(k0 + kb0 + i * 4) * N + (n0 + nb)];
    }
    __syncthreads();
#pragma unroll
    for (int kk = 0; kk < 32; ++kk) {
      float4 av = *reinterpret_cast<const float4*>(&As[kk][ty * 4]);
      float4 bv = *reinterpret_cast<const float4*>(&Bs[kk][tx * 4]);
      float a[4] = {av.x, av.y, av.z, av.w};
      float b[4] = {bv.x, bv.y, bv.z, bv.w};
#pragma unroll
      for (int i = 0; i < 4; ++i)
#pragma unroll
        for (int j = 0; j < 4; ++j) acc[i][j] = fmaf(a[i], b[j], acc[i][j]);
    }
    __syncthreads();
  }
#pragma unroll
  for (int i = 0; i < 4; ++i) {
    int m = m0 + ty * 4 + i;
    if (m < M) {
      float rs = rowscale ? rowscale[m] : 1.0f;
#pragma unroll
      for (int j = 0; j < 4; ++j) {
        int n = n0 + tx * 4 + j;
        float v = acc[i][j] * rs;
        if (bias) v += bias[n];
        C[(size_t)m * N + n] = v;
      }
    }
  }
}

// H[node] = relu( (sum_{e in CSR[node]} XW[src(e)]) * isr_in[node] + bias )
// 32 threads per node (128 channels as float4), 8 nodes per 256-thread block.
__global__ __launch_bounds__(256) void agg_kernel(
    const float* __restrict__ XW, const int* __restrict__ offs,
    const int* __restrict__ csr, const float* __restrict__ isr_in,
    const float* __restrict__ bias, float* __restrict__ H, int n) {
  int lane = threadIdx.x & 31;
  int node = blockIdx.x * 8 + (threadIdx.x >> 5);
  if (node >= n) return;
  int e0 = offs[node], e1 = offs[node + 1];
  float4 acc = make_float4(0.f, 0.f, 0.f, 0.f);
  for (int e = e0; e < e1; ++e) {
    int s = csr[e];
    float4 v = *reinterpret_cast<const float4*>(&XW[(size_t)s * 128 + lane * 4]);
    acc.x += v.x;
    acc.y += v.y;
    acc.z += v.z;
    acc.w += v.w;
  }
  float sc = isr_in[node];
  float4 b = *reinterpret_cast<const float4*>(&bias[lane * 4]);
  float4 o;
  o.x = fmaxf(fmaf(acc.x, sc, b.x), 0.f);
  o.y = fmaxf(fmaf(acc.y, sc, b.y), 0.f);
  o.z = fmaxf(fmaf(acc.z, sc, b.z), 0.f);
  o.w = fmaxf(fmaf(acc.w, sc, b.w), 0.f);
  *reinterpret_cast<float4*>(&H[(size_t)node * 128 + lane * 4]) = o;
}

// out[col] += column sums of X[n, ncol]; out must be pre-zeroed. ncol | 256.
__global__ __launch_bounds__(256) void colsum_kernel(const float* __restrict__ X,
                                                     float* __restrict__ out, int n, int ncol) {
  __shared__ float s[256];
  int col = threadIdx.x % ncol;
  int rpb = 256 / ncol;
  int rb = threadIdx.x / ncol;
  float acc = 0.f;
  for (int r = blockIdx.x * rpb + rb; r < n; r += gridDim.x * rpb)
    acc += X[(size_t)r * ncol + col];
  s[threadIdx.x] = acc;
  __syncthreads();
  if (threadIdx.x < ncol) {
    float v = 0.f;
    for (int i = 0; i < rpb; ++i) v += s[threadIdx.x + i * ncol];
    atomicAdd(&out[col], v);
  }
}

// out[col] = max over rows (X is relu output so >= 0; out pre-zeroed).
// Non-negative float bit patterns order like uints -> atomicMax on bits.
__global__ __launch_bounds__(256) void colmax_kernel(const float* __restrict__ X,
                                                     unsigned* __restrict__ out, int n, int ncol) {
  __shared__ float s[256];
  int col = threadIdx.x % ncol;
  int rpb = 256 / ncol;
  int rb = threadIdx.x / ncol;
  float acc = 0.f;
  for (int r = blockIdx.x * rpb + rb; r < n; r += gridDim.x * rpb)
    acc = fmaxf(acc, X[(size_t)r * ncol + col]);
  s[threadIdx.x] = acc;
  __syncthreads();
  if (threadIdx.x < ncol) {
    float v = s[threadIdx.x];
    for (int i = 1; i < rpb; ++i) v = fmaxf(v, s[threadIdx.x + i * ncol]);
    atomicMax(&out[col], __float_as_uint(v));
  }
}

// norm_embed(a) + norm_embed(f) then @ W_cls + b_cls. Single block of 128.
__global__ __launch_bounds__(128) void final_kernel(
    const float* __restrict__ emb_a_sum, const unsigned* __restrict__ emb_f_bits,
    const float* __restrict__ W_cls, const float* __restrict__ b_cls,
    float* __restrict__ out, float inv_n_apig, int ncls) {
  __shared__ float red[128];
  __shared__ float emb[128];
  int t = threadIdx.x;
  float a = emb_a_sum[t] * inv_n_apig;       // mean_nodes
  float f = __uint_as_float(emb_f_bits[t]);  // max_nodes

  float vals[2] = {a, f};
  float norms[2];
#pragma unroll
  for (int which = 0; which < 2; ++which) {
    float x = vals[which];
    red[t] = x;
    __syncthreads();
    for (int o = 64; o > 0; o >>= 1) {
      if (t < o) red[t] += red[t + o];
      __syncthreads();
    }
    float mean = red[0] / 128.f;
    __syncthreads();
    float d = x - mean;
    red[t] = d * d;
    __syncthreads();
    for (int o = 64; o > 0; o >>= 1) {
      if (t < o) red[t] += red[t + o];
      __syncthreads();
    }
    float stdv = sqrtf(red[0] / 127.f);  // unbiased (ddof=1)
    __syncthreads();
    float z = d / stdv;
    red[t] = z;
    __syncthreads();
    for (int o = 64; o > 0; o >>= 1) {
      if (t < o) red[t] = fminf(red[t], red[t + o]);
      __syncthreads();
    }
    float zmin = red[0];
    __syncthreads();
    red[t] = z;
    __syncthreads();
    for (int o = 64; o > 0; o >>= 1) {
      if (t < o) red[t] = fmaxf(red[t], red[t + o]);
      __syncthreads();
    }
    float zmax = red[0];
    __syncthreads();
    norms[which] = (z - zmin) / (zmax - zmin);
  }

  // softmax over length-1 axis == 1.0 -> emb = a_norm + f_norm
  emb[t] = norms[0] + norms[1];
  __syncthreads();
  if (t < ncls) {
    float acc = b_cls[t];
    for (int k = 0; k < 128; ++k) acc = fmaf(emb[k], W_cls[k * ncls + t], acc);
    out[t] = acc;
  }
}

extern "C" void kernel_launch(void* const* d_in, const int* in_sizes, int n_in,
                              void* d_out, int out_size, void* d_ws, size_t ws_size,
                              hipStream_t stream) {
  const float* apig_feat = (const float*)d_in[0];
  const float* fcg_feat = (const float*)d_in[1];
  const float* W_a1 = (const float*)d_in[2];
  const float* b_a1 = (const float*)d_in[3];
  const float* W_a2 = (const float*)d_in[4];
  const float* b_a2 = (const float*)d_in[5];
  const float* W_f1 = (const float*)d_in[6];
  const float* b_f1 = (const float*)d_in[7];
  const float* W_f2 = (const float*)d_in[8];
  const float* b_f2 = (const float*)d_in[9];
  const float* W1 = (const float*)d_in[10];
  const float* b1 = (const float*)d_in[11];
  const float* W2 = (const float*)d_in[12];
  const float* b2 = (const float*)d_in[13];
  // d_in[14]/d_in[15] (W_attn, b_attn): dead — softmax over length-1 axis == 1.
  const float* W_cls = (const float*)d_in[16];
  const float* b_cls = (const float*)d_in[17];
  const int* a_src = (const int*)d_in[18];
  const int* a_dst = (const int*)d_in[19];
  const int* f_src = (const int*)d_in[20];
  const int* f_dst = (const int*)d_in[21];

  const int hidden = in_sizes[3];             // 128
  const int united = in_sizes[11];            // 64
  const int ncls = in_sizes[17];              // 10
  const int apig_dim = in_sizes[2] / hidden;  // 256
  const int fcg_dim = in_sizes[6] / hidden;   // 128
  const int n_a = in_sizes[0] / apig_dim;     // 50000
  const int n_f = in_sizes[1] / fcg_dim;      // 100000
  const int e_a = in_sizes[18];               // 800000
  const int e_f = in_sizes[20];               // 1600000

  // ---- workspace carve-up (all 256B aligned) ----
  char* w = (char*)d_ws;
  auto alloc = [&](size_t bytes) -> void* {
    void* p = (void*)w;
    w += (bytes + 255) & ~(size_t)255;
    return p;
  };
  float* isr_out_a = (float*)alloc((size_t)n_a * 4);
  float* isr_in_a = (float*)alloc((size_t)n_a * 4);
  float* isr_out_f = (float*)alloc((size_t)n_f * 4);
  float* isr_in_f = (float*)alloc((size_t)n_f * 4);
  int* cnt_out_a = (int*)alloc((size_t)n_a * 4);
  int* cnt_in_a = (int*)alloc((size_t)n_a * 4);
  int* offs_a = (int*)alloc((size_t)(n_a + 1) * 4);
  int* cur_a = (int*)alloc((size_t)n_a * 4);
  int* csr_a = (int*)alloc((size_t)e_a * 4);
  int* cnt_out_f = (int*)alloc((size_t)n_f * 4);
  int* cnt_in_f = (int*)alloc((size_t)n_f * 4);
  int* offs_f = (int*)alloc((size_t)(n_f + 1) * 4);
  int* cur_f = (int*)alloc((size_t)n_f * 4);
  int* csr_f = (int*)alloc((size_t)e_f * 4);
  float* A1 = (float*)alloc((size_t)n_a * hidden * 4);
  float* A2 = (float*)alloc((size_t)n_a * hidden * 4);
  float* F1 = (float*)alloc((size_t)n_f * hidden * 4);
  float* F2 = (float*)alloc((size_t)n_f * hidden * 4);
  float* a_sum = (float*)alloc((size_t)united * 4);
  float* f_sum = (float*)alloc((size_t)united * 4);
  float* emb_a = (float*)alloc((size_t)hidden * 4);
  unsigned* emb_f = (unsigned*)alloc((size_t)hidden * 4);
  (void)ws_size;
  (void)n_in;
  (void)out_size;

  // ---- degrees + CSR (shared by both conv layers of each graph) ----
  hipMemsetAsync(cnt_out_a, 0, (size_t)n_a * 4, stream);
  hipMemsetAsync(cnt_in_a, 0, (size_t)n_a * 4, stream);
  hipMemsetAsync(cnt_out_f, 0, (size_t)n_f * 4, stream);
  hipMemsetAsync(cnt_in_f, 0, (size_t)n_f * 4, stream);
  count_kernel<<<(e_a + 255) / 256, 256, 0, stream>>>(a_src, a_dst, cnt_out_a, cnt_in_a, e_a);
  count_kernel<<<(e_f + 255) / 256, 256, 0, stream>>>(f_src, f_dst, cnt_out_f, cnt_in_f, e_f);
  isr_kernel<<<(n_a + 255) / 256, 256, 0, stream>>>(cnt_out_a, isr_out_a, n_a);
  isr_kernel<<<(n_a + 255) / 256, 256, 0, stream>>>(cnt_in_a, isr_in_a, n_a);
  isr_kernel<<<(n_f + 255) / 256, 256, 0, stream>>>(cnt_out_f, isr_out_f, n_f);
  isr_kernel<<<(n_f + 255) / 256, 256, 0, stream>>>(cnt_in_f, isr_in_f, n_f);
  scan_kernel<<<1, 1024, 0, stream>>>(cnt_in_a, offs_a, cur_a, n_a);
  scan_kernel<<<1, 1024, 0, stream>>>(cnt_in_f, offs_f, cur_f, n_f);
  csr_scatter_kernel<<<(e_a + 255) / 256, 256, 0, stream>>>(a_src, a_dst, cur_a, csr_a, e_a);
  csr_scatter_kernel<<<(e_f + 255) / 256, 256, 0, stream>>>(f_src, f_dst, cur_f, csr_f, e_f);

  dim3 blk(256);

  // ---- apig conv1: h_a1 = relu(agg((X@W_a1)*dout) * din + b_a1) ----
  gemm_kernel<<<dim3((n_a + 63) / 64, hidden / 64), blk, 0, stream>>>(
      apig_feat, W_a1, A1, n_a, hidden, apig_dim, nullptr, 0.f, isr_out_a, nullptr);
  agg_kernel<<<(n_a + 7) / 8, blk, 0, stream>>>(A1, offs_a, csr_a, isr_in_a, b_a1, A2, n_a);
  // a_enc(raw) = h_a1 @ W1 + b1  -> A1 ; a_sum = colsum(a_enc_raw)
  gemm_kernel<<<dim3((n_a + 63) / 64, united / 64), blk, 0, stream>>>(
      A2, W1, A1, n_a, united, hidden, nullptr, 0.f, nullptr, b1);
  hipMemsetAsync(a_sum, 0, (size_t)united * 4, stream);
  colsum_kernel<<<256, blk, 0, stream>>>(A1, a_sum, n_a, united);

  // ---- fcg conv1 ----
  gemm_kernel<<<dim3((n_f + 63) / 64, hidden / 64), blk, 0, stream>>>(
      fcg_feat, W_f1, F1, n_f, hidden, fcg_dim, nullptr, 0.f, isr_out_f, nullptr);
  agg_kernel<<<(n_f + 7) / 8, blk, 0, stream>>>(F1, offs_f, csr_f, isr_in_f, b_f1, F2, n_f);
  gemm_kernel<<<dim3((n_f + 63) / 64, united / 64), blk, 0, stream>>>(
      F2, W1, F1, n_f, united, hidden, nullptr, 0.f, nullptr, b1);
  hipMemsetAsync(f_sum, 0, (size_t)united * 4, stream);
  colsum_kernel<<<256, blk, 0, stream>>>(F1, f_sum, n_f, united);

  // ---- apig branch 2: a_dec = (a_enc + 0.1*f_sum)@W2 + b2; conv2; mean ----
  gemm_kernel<<<dim3((n_a + 63) / 64, hidden / 64), blk, 0, stream>>>(
      A1, W2, A2, n_a, hidden, united, f_sum, 0.1f, nullptr, b2);
  gemm_kernel<<<dim3((n_a + 63) / 64, hidden / 64), blk, 0, stream>>>(
      A2, W_a2, A1, n_a, hidden, hidden, nullptr, 0.f, isr_out_a, nullptr);
  agg_kernel<<<(n_a + 7) / 8, blk, 0, stream>>>(A1, offs_a, csr_a, isr_in_a, b_a2, A2, n_a);
  hipMemsetAsync(emb_a, 0, (size_t)hidden * 4, stream);
  colsum_kernel<<<256, blk, 0, stream>>>(A2, emb_a, n_a, hidden);

  // ---- fcg branch 2: f_dec = (f_enc + 0.1*a_sum)@W2 + b2; conv2; max ----
  gemm_kernel<<<dim3((n_f + 63) / 64, hidden / 64), blk, 0, stream>>>(
      F1, W2, F2, n_f, hidden, united, a_sum, 0.1f, nullptr, b2);
  gemm_kernel<<<dim3((n_f + 63) / 64, hidden / 64), blk, 0, stream>>>(
      F2, W_f2, F1, n_f, hidden, hidden, nullptr, 0.f, isr_out_f, nullptr);
  agg_kernel<<<(n_f + 7) / 8, blk, 0, stream>>>(F1, offs_f, csr_f, isr_in_f, b_f2, F2, n_f);
  hipMemsetAsync(emb_f, 0, (size_t)hidden * 4, stream);
  colmax_kernel<<<256, blk, 0, stream>>>(F2, emb_f, n_f, hidden);

  // ---- head ----
  final_kernel<<<1, 128, 0, stream>>>(emb_a, emb_f, W_cls, b_cls, (float*)d_out,
                                      1.0f / (float)n_a, ncls);
}

// Round 3
// 1389.390 us; speedup vs baseline: 1.2226x; 1.2226x over previous
//
#include <hip/hip_runtime.h>
#include <math.h>

// ---------------------------------------------------------------------------
// MultiGraphClassifier on MI355X.
// Pipeline: 2x GraphConv per graph + cross-graph fusion + tiny head.
// Strategy: CSR build per call (counting sort with 3-phase multi-block scan),
// gather-side aggregation (no fp32 atomics on feature data), fp32 LDS-tiled
// GEMMs with fused degree-scale / bias / fusion-add epilogues.
// Note: softmax over a length-1 axis == 1.0, so emb = norm(a) + norm(f);
// W_attn / b_attn are mathematically dead.
// R1: replaced 1-block scan (2x234us, 28% of runtime) with 3-phase scan.
// R2: container infra failure — identical resubmit.
// ---------------------------------------------------------------------------

__global__ void count_kernel(const int* __restrict__ src, const int* __restrict__ dst,
                             int* __restrict__ cnt_out, int* __restrict__ cnt_in, int E) {
  int e = blockIdx.x * blockDim.x + threadIdx.x;
  if (e < E) {
    atomicAdd(&cnt_out[src[e]], 1);
    atomicAdd(&cnt_in[dst[e]], 1);
  }
}

// isr = 1/sqrt(clip(deg,1)) for both out- and in-degree arrays in one pass.
__global__ void isr2_kernel(const int* __restrict__ cnt_out, const int* __restrict__ cnt_in,
                            float* __restrict__ isr_out, float* __restrict__ isr_in, int n) {
  int i = blockIdx.x * blockDim.x + threadIdx.x;
  if (i < n) {
    int co = cnt_out[i];
    if (co < 1) co = 1;
    isr_out[i] = 1.0f / sqrtf((float)co);
    int ci = cnt_in[i];
    if (ci < 1) ci = 1;
    isr_in[i] = 1.0f / sqrtf((float)ci);
  }
}

// ---- 3-phase exclusive scan over cnt[n] (n <= ~100k), tile = 4096 ----
// Phase 1: per-block (4096-elem) sums.
__global__ __launch_bounds__(256) void blocksum_kernel(const int* __restrict__ cnt,
                                                       int* __restrict__ blksum, int n) {
  __shared__ int red[256];
  int base = blockIdx.x * 4096 + threadIdx.x * 16;
  int s = 0;
#pragma unroll
  for (int j = 0; j < 16; ++j) {
    int idx = base + j;
    if (idx < n) s += cnt[idx];
  }
  red[threadIdx.x] = s;
  __syncthreads();
  for (int o = 128; o > 0; o >>= 1) {
    if (threadIdx.x < o) red[threadIdx.x] += red[threadIdx.x + o];
    __syncthreads();
  }
  if (threadIdx.x == 0) blksum[blockIdx.x] = red[0];
}

// Phase 2: exclusive scan of B (<=64) block sums in one wave, in place.
__global__ __launch_bounds__(64) void blkscan_kernel(int* __restrict__ blksum, int B) {
  int t = threadIdx.x;
  int v = (t < B) ? blksum[t] : 0;
  int inc = v;
#pragma unroll
  for (int o = 1; o < 64; o <<= 1) {
    int u = __shfl_up(inc, o, 64);
    if (t >= o) inc += u;
  }
  if (t < B) blksum[t] = inc - v;  // exclusive
}

// Phase 3: per-block local scan + coalesced offs/cursor write; offs[n]=total.
__global__ __launch_bounds__(256) void offsets_kernel(const int* __restrict__ cnt,
                                                      const int* __restrict__ blkoffs,
                                                      int* __restrict__ offs,
                                                      int* __restrict__ cursor, int n) {
  __shared__ int part[256];
  int base = blockIdx.x * 4096 + threadIdx.x * 16;
  int c[16];
  int s = 0;
#pragma unroll
  for (int j = 0; j < 16; ++j) {
    int idx = base + j;
    c[j] = (idx < n) ? cnt[idx] : 0;
    s += c[j];
  }
  part[threadIdx.x] = s;
  __syncthreads();
  for (int o = 1; o < 256; o <<= 1) {
    int v = (threadIdx.x >= o) ? part[threadIdx.x - o] : 0;
    __syncthreads();
    part[threadIdx.x] += v;
    __syncthreads();
  }
  int run = blkoffs[blockIdx.x] + part[threadIdx.x] - s;  // exclusive start
#pragma unroll
  for (int j = 0; j < 16; ++j) {
    int idx = base + j;
    if (idx < n) {
      offs[idx] = run;
      cursor[idx] = run;
      run += c[j];
      if (idx == n - 1) offs[n] = run;
    }
  }
}

__global__ void csr_scatter_kernel(const int* __restrict__ src, const int* __restrict__ dst,
                                   int* __restrict__ cursor, int* __restrict__ csr, int E) {
  int e = blockIdx.x * blockDim.x + threadIdx.x;
  if (e < E) {
    int p = atomicAdd(&cursor[dst[e]], 1);
    csr[p] = src[e];
  }
}

// C[M,N] = (A[M,K] (+ add_scale*add_vec[K])) @ B[K,N]  * rowscale[M]?  + bias[N]?
// Requires: N % 64 == 0, K % 32 == 0. 64x64 block tile, 4x4 per thread.
__global__ __launch_bounds__(256) void gemm_kernel(
    const float* __restrict__ A, const float* __restrict__ B, float* __restrict__ C,
    int M, int N, int K,
    const float* __restrict__ add_vec, float add_scale,
    const float* __restrict__ rowscale, const float* __restrict__ bias) {
  __shared__ float As[32][68];  // [k][m], +4 pad keeps float4 alignment, no conflicts
  __shared__ float Bs[32][68];  // [k][n]
  const int m0 = blockIdx.x * 64;
  const int n0 = blockIdx.y * 64;
  const int tid = threadIdx.x;
  const int tx = tid & 15, ty = tid >> 4;
  const int ka = tid & 31, ra0 = tid >> 5;  // A-tile loader coords
  const int nb = tid & 63, kb0 = tid >> 6;  // B-tile loader coords
  float acc[4][4] = {};
  for (int k0 = 0; k0 < K; k0 += 32) {
#pragma unroll
    for (int i = 0; i < 8; ++i) {
      int m = m0 + ra0 + i * 8;
      float v = 0.f;
      if (m < M) {
        v = A[(size_t)m * K + (k0 + ka)];
        if (add_vec) v += add_scale * add_vec[k0 + ka];
      }
      As[ka][ra0 + i * 8] = v;
    }
#pragma unroll
    for (int i = 0; i < 8; ++i) {
      Bs[kb0 + i * 4][nb] = B[(size_t)(k0 + kb0 + i * 4) * N + (n0 + nb)];
    }
    __syncthreads();
#pragma unroll
    for (int kk = 0; kk < 32; ++kk) {
      float4 av = *reinterpret_cast<const float4*>(&As[kk][ty * 4]);
      float4 bv = *reinterpret_cast<const float4*>(&Bs[kk][tx * 4]);
      float a[4] = {av.x, av.y, av.z, av.w};
      float b[4] = {bv.x, bv.y, bv.z, bv.w};
#pragma unroll
      for (int i = 0; i < 4; ++i)
#pragma unroll
        for (int j = 0; j < 4; ++j) acc[i][j] = fmaf(a[i], b[j], acc[i][j]);
    }
    __syncthreads();
  }
#pragma unroll
  for (int i = 0; i < 4; ++i) {
    int m = m0 + ty * 4 + i;
    if (m < M) {
      float rs = rowscale ? rowscale[m] : 1.0f;
#pragma unroll
      for (int j = 0; j < 4; ++j) {
        int n = n0 + tx * 4 + j;
        float v = acc[i][j] * rs;
        if (bias) v += bias[n];
        C[(size_t)m * N + n] = v;
      }
    }
  }
}

// H[node] = relu( (sum_{e in CSR[node]} XW[src(e)]) * isr_in[node] + bias )
// 32 threads per node (128 channels as float4), 8 nodes per 256-thread block.
__global__ __launch_bounds__(256) void agg_kernel(
    const float* __restrict__ XW, const int* __restrict__ offs,
    const int* __restrict__ csr, const float* __restrict__ isr_in,
    const float* __restrict__ bias, float* __restrict__ H, int n) {
  int lane = threadIdx.x & 31;
  int node = blockIdx.x * 8 + (threadIdx.x >> 5);
  if (node >= n) return;
  int e0 = offs[node], e1 = offs[node + 1];
  float4 acc = make_float4(0.f, 0.f, 0.f, 0.f);
  for (int e = e0; e < e1; ++e) {
    int s = csr[e];
    float4 v = *reinterpret_cast<const float4*>(&XW[(size_t)s * 128 + lane * 4]);
    acc.x += v.x;
    acc.y += v.y;
    acc.z += v.z;
    acc.w += v.w;
  }
  float sc = isr_in[node];
  float4 b = *reinterpret_cast<const float4*>(&bias[lane * 4]);
  float4 o;
  o.x = fmaxf(fmaf(acc.x, sc, b.x), 0.f);
  o.y = fmaxf(fmaf(acc.y, sc, b.y), 0.f);
  o.z = fmaxf(fmaf(acc.z, sc, b.z), 0.f);
  o.w = fmaxf(fmaf(acc.w, sc, b.w), 0.f);
  *reinterpret_cast<float4*>(&H[(size_t)node * 128 + lane * 4]) = o;
}

// out[col] += column sums of X[n, ncol]; out must be pre-zeroed. ncol | 256.
__global__ __launch_bounds__(256) void colsum_kernel(const float* __restrict__ X,
                                                     float* __restrict__ out, int n, int ncol) {
  __shared__ float s[256];
  int col = threadIdx.x % ncol;
  int rpb = 256 / ncol;
  int rb = threadIdx.x / ncol;
  float acc = 0.f;
  for (int r = blockIdx.x * rpb + rb; r < n; r += gridDim.x * rpb)
    acc += X[(size_t)r * ncol + col];
  s[threadIdx.x] = acc;
  __syncthreads();
  if (threadIdx.x < ncol) {
    float v = 0.f;
    for (int i = 0; i < rpb; ++i) v += s[threadIdx.x + i * ncol];
    atomicAdd(&out[col], v);
  }
}

// out[col] = max over rows (X is relu output so >= 0; out pre-zeroed).
// Non-negative float bit patterns order like uints -> atomicMax on bits.
__global__ __launch_bounds__(256) void colmax_kernel(const float* __restrict__ X,
                                                     unsigned* __restrict__ out, int n, int ncol) {
  __shared__ float s[256];
  int col = threadIdx.x % ncol;
  int rpb = 256 / ncol;
  int rb = threadIdx.x / ncol;
  float acc = 0.f;
  for (int r = blockIdx.x * rpb + rb; r < n; r += gridDim.x * rpb)
    acc = fmaxf(acc, X[(size_t)r * ncol + col]);
  s[threadIdx.x] = acc;
  __syncthreads();
  if (threadIdx.x < ncol) {
    float v = s[threadIdx.x];
    for (int i = 1; i < rpb; ++i) v = fmaxf(v, s[threadIdx.x + i * ncol]);
    atomicMax(&out[col], __float_as_uint(v));
  }
}

// norm_embed(a) + norm_embed(f) then @ W_cls + b_cls. Single block of 128.
__global__ __launch_bounds__(128) void final_kernel(
    const float* __restrict__ emb_a_sum, const unsigned* __restrict__ emb_f_bits,
    const float* __restrict__ W_cls, const float* __restrict__ b_cls,
    float* __restrict__ out, float inv_n_apig, int ncls) {
  __shared__ float red[128];
  __shared__ float emb[128];
  int t = threadIdx.x;
  float a = emb_a_sum[t] * inv_n_apig;       // mean_nodes
  float f = __uint_as_float(emb_f_bits[t]);  // max_nodes

  float vals[2] = {a, f};
  float norms[2];
#pragma unroll
  for (int which = 0; which < 2; ++which) {
    float x = vals[which];
    red[t] = x;
    __syncthreads();
    for (int o = 64; o > 0; o >>= 1) {
      if (t < o) red[t] += red[t + o];
      __syncthreads();
    }
    float mean = red[0] / 128.f;
    __syncthreads();
    float d = x - mean;
    red[t] = d * d;
    __syncthreads();
    for (int o = 64; o > 0; o >>= 1) {
      if (t < o) red[t] += red[t + o];
      __syncthreads();
    }
    float stdv = sqrtf(red[0] / 127.f);  // unbiased (ddof=1)
    __syncthreads();
    float z = d / stdv;
    red[t] = z;
    __syncthreads();
    for (int o = 64; o > 0; o >>= 1) {
      if (t < o) red[t] = fminf(red[t], red[t + o]);
      __syncthreads();
    }
    float zmin = red[0];
    __syncthreads();
    red[t] = z;
    __syncthreads();
    for (int o = 64; o > 0; o >>= 1) {
      if (t < o) red[t] = fmaxf(red[t], red[t + o]);
      __syncthreads();
    }
    float zmax = red[0];
    __syncthreads();
    norms[which] = (z - zmin) / (zmax - zmin);
  }

  // softmax over length-1 axis == 1.0 -> emb = a_norm + f_norm
  emb[t] = norms[0] + norms[1];
  __syncthreads();
  if (t < ncls) {
    float acc = b_cls[t];
    for (int k = 0; k < 128; ++k) acc = fmaf(emb[k], W_cls[k * ncls + t], acc);
    out[t] = acc;
  }
}

extern "C" void kernel_launch(void* const* d_in, const int* in_sizes, int n_in,
                              void* d_out, int out_size, void* d_ws, size_t ws_size,
                              hipStream_t stream) {
  const float* apig_feat = (const float*)d_in[0];
  const float* fcg_feat = (const float*)d_in[1];
  const float* W_a1 = (const float*)d_in[2];
  const float* b_a1 = (const float*)d_in[3];
  const float* W_a2 = (const float*)d_in[4];
  const float* b_a2 = (const float*)d_in[5];
  const float* W_f1 = (const float*)d_in[6];
  const float* b_f1 = (const float*)d_in[7];
  const float* W_f2 = (const float*)d_in[8];
  const float* b_f2 = (const float*)d_in[9];
  const float* W1 = (const float*)d_in[10];
  const float* b1 = (const float*)d_in[11];
  const float* W2 = (const float*)d_in[12];
  const float* b2 = (const float*)d_in[13];
  // d_in[14]/d_in[15] (W_attn, b_attn): dead — softmax over length-1 axis == 1.
  const float* W_cls = (const float*)d_in[16];
  const float* b_cls = (const float*)d_in[17];
  const int* a_src = (const int*)d_in[18];
  const int* a_dst = (const int*)d_in[19];
  const int* f_src = (const int*)d_in[20];
  const int* f_dst = (const int*)d_in[21];

  const int hidden = in_sizes[3];             // 128
  const int united = in_sizes[11];            // 64
  const int ncls = in_sizes[17];              // 10
  const int apig_dim = in_sizes[2] / hidden;  // 256
  const int fcg_dim = in_sizes[6] / hidden;   // 128
  const int n_a = in_sizes[0] / apig_dim;     // 50000
  const int n_f = in_sizes[1] / fcg_dim;      // 100000
  const int e_a = in_sizes[18];               // 800000
  const int e_f = in_sizes[20];               // 1600000

  // ---- workspace carve-up (all 256B aligned) ----
  char* w = (char*)d_ws;
  auto alloc = [&](size_t bytes) -> void* {
    void* p = (void*)w;
    w += (bytes + 255) & ~(size_t)255;
    return p;
  };
  float* isr_out_a = (float*)alloc((size_t)n_a * 4);
  float* isr_in_a = (float*)alloc((size_t)n_a * 4);
  float* isr_out_f = (float*)alloc((size_t)n_f * 4);
  float* isr_in_f = (float*)alloc((size_t)n_f * 4);
  int* cnt_out_a = (int*)alloc((size_t)n_a * 4);
  int* cnt_in_a = (int*)alloc((size_t)n_a * 4);
  int* offs_a = (int*)alloc((size_t)(n_a + 1) * 4);
  int* cur_a = (int*)alloc((size_t)n_a * 4);
  int* csr_a = (int*)alloc((size_t)e_a * 4);
  int* cnt_out_f = (int*)alloc((size_t)n_f * 4);
  int* cnt_in_f = (int*)alloc((size_t)n_f * 4);
  int* offs_f = (int*)alloc((size_t)(n_f + 1) * 4);
  int* cur_f = (int*)alloc((size_t)n_f * 4);
  int* csr_f = (int*)alloc((size_t)e_f * 4);
  int* blksum_a = (int*)alloc((size_t)64 * 4);
  int* blksum_f = (int*)alloc((size_t)64 * 4);
  float* A1 = (float*)alloc((size_t)n_a * hidden * 4);
  float* A2 = (float*)alloc((size_t)n_a * hidden * 4);
  float* F1 = (float*)alloc((size_t)n_f * hidden * 4);
  float* F2 = (float*)alloc((size_t)n_f * hidden * 4);
  float* a_sum = (float*)alloc((size_t)united * 4);
  float* f_sum = (float*)alloc((size_t)united * 4);
  float* emb_a = (float*)alloc((size_t)hidden * 4);
  unsigned* emb_f = (unsigned*)alloc((size_t)hidden * 4);
  (void)ws_size;
  (void)n_in;
  (void)out_size;

  const int Ba = (n_a + 4095) / 4096;  // 13
  const int Bf = (n_f + 4095) / 4096;  // 25

  // ---- degrees + CSR (shared by both conv layers of each graph) ----
  hipMemsetAsync(cnt_out_a, 0, (size_t)n_a * 4, stream);
  hipMemsetAsync(cnt_in_a, 0, (size_t)n_a * 4, stream);
  hipMemsetAsync(cnt_out_f, 0, (size_t)n_f * 4, stream);
  hipMemsetAsync(cnt_in_f, 0, (size_t)n_f * 4, stream);
  count_kernel<<<(e_a + 255) / 256, 256, 0, stream>>>(a_src, a_dst, cnt_out_a, cnt_in_a, e_a);
  count_kernel<<<(e_f + 255) / 256, 256, 0, stream>>>(f_src, f_dst, cnt_out_f, cnt_in_f, e_f);
  isr2_kernel<<<(n_a + 255) / 256, 256, 0, stream>>>(cnt_out_a, cnt_in_a, isr_out_a, isr_in_a, n_a);
  isr2_kernel<<<(n_f + 255) / 256, 256, 0, stream>>>(cnt_out_f, cnt_in_f, isr_out_f, isr_in_f, n_f);
  // 3-phase exclusive scan of cnt_in -> offs (+ cursor copy)
  blocksum_kernel<<<Ba, 256, 0, stream>>>(cnt_in_a, blksum_a, n_a);
  blocksum_kernel<<<Bf, 256, 0, stream>>>(cnt_in_f, blksum_f, n_f);
  blkscan_kernel<<<1, 64, 0, stream>>>(blksum_a, Ba);
  blkscan_kernel<<<1, 64, 0, stream>>>(blksum_f, Bf);
  offsets_kernel<<<Ba, 256, 0, stream>>>(cnt_in_a, blksum_a, offs_a, cur_a, n_a);
  offsets_kernel<<<Bf, 256, 0, stream>>>(cnt_in_f, blksum_f, offs_f, cur_f, n_f);
  csr_scatter_kernel<<<(e_a + 255) / 256, 256, 0, stream>>>(a_src, a_dst, cur_a, csr_a, e_a);
  csr_scatter_kernel<<<(e_f + 255) / 256, 256, 0, stream>>>(f_src, f_dst, cur_f, csr_f, e_f);

  dim3 blk(256);

  // ---- apig conv1: h_a1 = relu(agg((X@W_a1)*dout) * din + b_a1) ----
  gemm_kernel<<<dim3((n_a + 63) / 64, hidden / 64), blk, 0, stream>>>(
      apig_feat, W_a1, A1, n_a, hidden, apig_dim, nullptr, 0.f, isr_out_a, nullptr);
  agg_kernel<<<(n_a + 7) / 8, blk, 0, stream>>>(A1, offs_a, csr_a, isr_in_a, b_a1, A2, n_a);
  // a_enc(raw) = h_a1 @ W1 + b1  -> A1 ; a_sum = colsum(a_enc_raw)
  gemm_kernel<<<dim3((n_a + 63) / 64, united / 64), blk, 0, stream>>>(
      A2, W1, A1, n_a, united, hidden, nullptr, 0.f, nullptr, b1);
  hipMemsetAsync(a_sum, 0, (size_t)united * 4, stream);
  colsum_kernel<<<256, blk, 0, stream>>>(A1, a_sum, n_a, united);

  // ---- fcg conv1 ----
  gemm_kernel<<<dim3((n_f + 63) / 64, hidden / 64), blk, 0, stream>>>(
      fcg_feat, W_f1, F1, n_f, hidden, fcg_dim, nullptr, 0.f, isr_out_f, nullptr);
  agg_kernel<<<(n_f + 7) / 8, blk, 0, stream>>>(F1, offs_f, csr_f, isr_in_f, b_f1, F2, n_f);
  gemm_kernel<<<dim3((n_f + 63) / 64, united / 64), blk, 0, stream>>>(
      F2, W1, F1, n_f, united, hidden, nullptr, 0.f, nullptr, b1);
  hipMemsetAsync(f_sum, 0, (size_t)united * 4, stream);
  colsum_kernel<<<256, blk, 0, stream>>>(F1, f_sum, n_f, united);

  // ---- apig branch 2: a_dec = (a_enc + 0.1*f_sum)@W2 + b2; conv2; mean ----
  gemm_kernel<<<dim3((n_a + 63) / 64, hidden / 64), blk, 0, stream>>>(
      A1, W2, A2, n_a, hidden, united, f_sum, 0.1f, nullptr, b2);
  gemm_kernel<<<dim3((n_a + 63) / 64, hidden / 64), blk, 0, stream>>>(
      A2, W_a2, A1, n_a, hidden, hidden, nullptr, 0.f, isr_out_a, nullptr);
  agg_kernel<<<(n_a + 7) / 8, blk, 0, stream>>>(A1, offs_a, csr_a, isr_in_a, b_a2, A2, n_a);
  hipMemsetAsync(emb_a, 0, (size_t)hidden * 4, stream);
  colsum_kernel<<<256, blk, 0, stream>>>(A2, emb_a, n_a, hidden);

  // ---- fcg branch 2: f_dec = (f_enc + 0.1*a_sum)@W2 + b2; conv2; max ----
  gemm_kernel<<<dim3((n_f + 63) / 64, hidden / 64), blk, 0, stream>>>(
      F1, W2, F2, n_f, hidden, united, a_sum, 0.1f, nullptr, b2);
  gemm_kernel<<<dim3((n_f + 63) / 64, hidden / 64), blk, 0, stream>>>(
      F2, W_f2, F1, n_f, hidden, hidden, nullptr, 0.f, isr_out_f, nullptr);
  agg_kernel<<<(n_f + 7) / 8, blk, 0, stream>>>(F1, offs_f, csr_f, isr_in_f, b_f2, F2, n_f);
  hipMemsetAsync(emb_f, 0, (size_t)hidden * 4, stream);
  colmax_kernel<<<256, blk, 0, stream>>>(F2, emb_f, n_f, hidden);

  // ---- head ----
  final_kernel<<<1, 128, 0, stream>>>(emb_a, emb_f, W_cls, b_cls, (float*)d_out,
                                      1.0f / (float)n_a, ncls);
}

// Round 4
// 1313.631 us; speedup vs baseline: 1.2931x; 1.0577x over previous
//
#include <hip/hip_runtime.h>
#include <math.h>

// ---------------------------------------------------------------------------
// MultiGraphClassifier on MI355X.
// Pipeline: 2x GraphConv per graph + cross-graph fusion + tiny head.
// Strategy: CSR build per call (rank-capturing counting sort, atomic-free
// scatter), gather-side aggregation (no fp32 atomics on feature data),
// fp32 LDS-tiled GEMMs with fused degree-scale / bias / fusion-add epilogues.
// Note: softmax over a length-1 axis == 1.0, so emb = norm(a) + norm(f);
// W_attn / b_attn are mathematically dead.
// R1: replaced 1-block scan (2x234us, 28% of runtime) with 3-phase scan.
// R3: scatter had 105MB WRITE_SIZE = 1.6M memory-side atomics x 64B.
//     Capture rank in count_kernel's existing atomicAdd return; scatter is
//     now atomic-free (plain store to unique slot).
// ---------------------------------------------------------------------------

__global__ void count_kernel(const int* __restrict__ src, const int* __restrict__ dst,
                             int* __restrict__ cnt_out, int* __restrict__ cnt_in,
                             int* __restrict__ rank, int E) {
  int e = blockIdx.x * blockDim.x + threadIdx.x;
  if (e < E) {
    atomicAdd(&cnt_out[src[e]], 1);
    rank[e] = atomicAdd(&cnt_in[dst[e]], 1);  // stable slot within dst bucket
  }
}

// isr = 1/sqrt(clip(deg,1)) for both out- and in-degree arrays in one pass.
__global__ void isr2_kernel(const int* __restrict__ cnt_out, const int* __restrict__ cnt_in,
                            float* __restrict__ isr_out, float* __restrict__ isr_in, int n) {
  int i = blockIdx.x * blockDim.x + threadIdx.x;
  if (i < n) {
    int co = cnt_out[i];
    if (co < 1) co = 1;
    isr_out[i] = 1.0f / sqrtf((float)co);
    int ci = cnt_in[i];
    if (ci < 1) ci = 1;
    isr_in[i] = 1.0f / sqrtf((float)ci);
  }
}

// ---- 3-phase exclusive scan over cnt[n] (n <= ~100k), tile = 4096 ----
// Phase 1: per-block (4096-elem) sums.
__global__ __launch_bounds__(256) void blocksum_kernel(const int* __restrict__ cnt,
                                                       int* __restrict__ blksum, int n) {
  __shared__ int red[256];
  int base = blockIdx.x * 4096 + threadIdx.x * 16;
  int s = 0;
#pragma unroll
  for (int j = 0; j < 16; ++j) {
    int idx = base + j;
    if (idx < n) s += cnt[idx];
  }
  red[threadIdx.x] = s;
  __syncthreads();
  for (int o = 128; o > 0; o >>= 1) {
    if (threadIdx.x < o) red[threadIdx.x] += red[threadIdx.x + o];
    __syncthreads();
  }
  if (threadIdx.x == 0) blksum[blockIdx.x] = red[0];
}

// Phase 2: exclusive scan of B (<=64) block sums in one wave, in place.
__global__ __launch_bounds__(64) void blkscan_kernel(int* __restrict__ blksum, int B) {
  int t = threadIdx.x;
  int v = (t < B) ? blksum[t] : 0;
  int inc = v;
#pragma unroll
  for (int o = 1; o < 64; o <<= 1) {
    int u = __shfl_up(inc, o, 64);
    if (t >= o) inc += u;
  }
  if (t < B) blksum[t] = inc - v;  // exclusive
}

// Phase 3: per-block local scan + coalesced offs write; offs[n]=total.
__global__ __launch_bounds__(256) void offsets_kernel(const int* __restrict__ cnt,
                                                      const int* __restrict__ blkoffs,
                                                      int* __restrict__ offs, int n) {
  __shared__ int part[256];
  int base = blockIdx.x * 4096 + threadIdx.x * 16;
  int c[16];
  int s = 0;
#pragma unroll
  for (int j = 0; j < 16; ++j) {
    int idx = base + j;
    c[j] = (idx < n) ? cnt[idx] : 0;
    s += c[j];
  }
  part[threadIdx.x] = s;
  __syncthreads();
  for (int o = 1; o < 256; o <<= 1) {
    int v = (threadIdx.x >= o) ? part[threadIdx.x - o] : 0;
    __syncthreads();
    part[threadIdx.x] += v;
    __syncthreads();
  }
  int run = blkoffs[blockIdx.x] + part[threadIdx.x] - s;  // exclusive start
#pragma unroll
  for (int j = 0; j < 16; ++j) {
    int idx = base + j;
    if (idx < n) {
      offs[idx] = run;
      run += c[j];
      if (idx == n - 1) offs[n] = run;
    }
  }
}

// Atomic-free scatter: slot = offs[dst] + rank (unique by construction).
__global__ void csr_scatter_kernel(const int* __restrict__ src, const int* __restrict__ dst,
                                   const int* __restrict__ offs, const int* __restrict__ rank,
                                   int* __restrict__ csr, int E) {
  int e = blockIdx.x * blockDim.x + threadIdx.x;
  if (e < E) {
    csr[offs[dst[e]] + rank[e]] = src[e];
  }
}

// C[M,N] = (A[M,K] (+ add_scale*add_vec[K])) @ B[K,N]  * rowscale[M]?  + bias[N]?
// Requires: N % 64 == 0, K % 32 == 0. 64x64 block tile, 4x4 per thread.
__global__ __launch_bounds__(256) void gemm_kernel(
    const float* __restrict__ A, const float* __restrict__ B, float* __restrict__ C,
    int M, int N, int K,
    const float* __restrict__ add_vec, float add_scale,
    const float* __restrict__ rowscale, const float* __restrict__ bias) {
  __shared__ float As[32][68];  // [k][m], +4 pad keeps float4 alignment, no conflicts
  __shared__ float Bs[32][68];  // [k][n]
  const int m0 = blockIdx.x * 64;
  const int n0 = blockIdx.y * 64;
  const int tid = threadIdx.x;
  const int tx = tid & 15, ty = tid >> 4;
  const int ka = tid & 31, ra0 = tid >> 5;  // A-tile loader coords
  const int nb = tid & 63, kb0 = tid >> 6;  // B-tile loader coords
  float acc[4][4] = {};
  for (int k0 = 0; k0 < K; k0 += 32) {
#pragma unroll
    for (int i = 0; i < 8; ++i) {
      int m = m0 + ra0 + i * 8;
      float v = 0.f;
      if (m < M) {
        v = A[(size_t)m * K + (k0 + ka)];
        if (add_vec) v += add_scale * add_vec[k0 + ka];
      }
      As[ka][ra0 + i * 8] = v;
    }
#pragma unroll
    for (int i = 0; i < 8; ++i) {
      Bs[kb0 + i * 4][nb] = B[(size_t)(k0 + kb0 + i * 4) * N + (n0 + nb)];
    }
    __syncthreads();
#pragma unroll
    for (int kk = 0; kk < 32; ++kk) {
      float4 av = *reinterpret_cast<const float4*>(&As[kk][ty * 4]);
      float4 bv = *reinterpret_cast<const float4*>(&Bs[kk][tx * 4]);
      float a[4] = {av.x, av.y, av.z, av.w};
      float b[4] = {bv.x, bv.y, bv.z, bv.w};
#pragma unroll
      for (int i = 0; i < 4; ++i)
#pragma unroll
        for (int j = 0; j < 4; ++j) acc[i][j] = fmaf(a[i], b[j], acc[i][j]);
    }
    __syncthreads();
  }
#pragma unroll
  for (int i = 0; i < 4; ++i) {
    int m = m0 + ty * 4 + i;
    if (m < M) {
      float rs = rowscale ? rowscale[m] : 1.0f;
#pragma unroll
      for (int j = 0; j < 4; ++j) {
        int n = n0 + tx * 4 + j;
        float v = acc[i][j] * rs;
        if (bias) v += bias[n];
        C[(size_t)m * N + n] = v;
      }
    }
  }
}

// H[node] = relu( (sum_{e in CSR[node]} XW[src(e)]) * isr_in[node] + bias )
// 32 threads per node (128 channels as float4), 8 nodes per 256-thread block.
__global__ __launch_bounds__(256) void agg_kernel(
    const float* __restrict__ XW, const int* __restrict__ offs,
    const int* __restrict__ csr, const float* __restrict__ isr_in,
    const float* __restrict__ bias, float* __restrict__ H, int n) {
  int lane = threadIdx.x & 31;
  int node = blockIdx.x * 8 + (threadIdx.x >> 5);
  if (node >= n) return;
  int e0 = offs[node], e1 = offs[node + 1];
  float4 acc = make_float4(0.f, 0.f, 0.f, 0.f);
  for (int e = e0; e < e1; ++e) {
    int s = csr[e];
    float4 v = *reinterpret_cast<const float4*>(&XW[(size_t)s * 128 + lane * 4]);
    acc.x += v.x;
    acc.y += v.y;
    acc.z += v.z;
    acc.w += v.w;
  }
  float sc = isr_in[node];
  float4 b = *reinterpret_cast<const float4*>(&bias[lane * 4]);
  float4 o;
  o.x = fmaxf(fmaf(acc.x, sc, b.x), 0.f);
  o.y = fmaxf(fmaf(acc.y, sc, b.y), 0.f);
  o.z = fmaxf(fmaf(acc.z, sc, b.z), 0.f);
  o.w = fmaxf(fmaf(acc.w, sc, b.w), 0.f);
  *reinterpret_cast<float4*>(&H[(size_t)node * 128 + lane * 4]) = o;
}

// out[col] += column sums of X[n, ncol]; out must be pre-zeroed. ncol | 256.
__global__ __launch_bounds__(256) void colsum_kernel(const float* __restrict__ X,
                                                     float* __restrict__ out, int n, int ncol) {
  __shared__ float s[256];
  int col = threadIdx.x % ncol;
  int rpb = 256 / ncol;
  int rb = threadIdx.x / ncol;
  float acc = 0.f;
  for (int r = blockIdx.x * rpb + rb; r < n; r += gridDim.x * rpb)
    acc += X[(size_t)r * ncol + col];
  s[threadIdx.x] = acc;
  __syncthreads();
  if (threadIdx.x < ncol) {
    float v = 0.f;
    for (int i = 0; i < rpb; ++i) v += s[threadIdx.x + i * ncol];
    atomicAdd(&out[col], v);
  }
}

// out[col] = max over rows (X is relu output so >= 0; out pre-zeroed).
// Non-negative float bit patterns order like uints -> atomicMax on bits.
__global__ __launch_bounds__(256) void colmax_kernel(const float* __restrict__ X,
                                                     unsigned* __restrict__ out, int n, int ncol) {
  __shared__ float s[256];
  int col = threadIdx.x % ncol;
  int rpb = 256 / ncol;
  int rb = threadIdx.x / ncol;
  float acc = 0.f;
  for (int r = blockIdx.x * rpb + rb; r < n; r += gridDim.x * rpb)
    acc = fmaxf(acc, X[(size_t)r * ncol + col]);
  s[threadIdx.x] = acc;
  __syncthreads();
  if (threadIdx.x < ncol) {
    float v = s[threadIdx.x];
    for (int i = 1; i < rpb; ++i) v = fmaxf(v, s[threadIdx.x + i * ncol]);
    atomicMax(&out[col], __float_as_uint(v));
  }
}

// norm_embed(a) + norm_embed(f) then @ W_cls + b_cls. Single block of 128.
__global__ __launch_bounds__(128) void final_kernel(
    const float* __restrict__ emb_a_sum, const unsigned* __restrict__ emb_f_bits,
    const float* __restrict__ W_cls, const float* __restrict__ b_cls,
    float* __restrict__ out, float inv_n_apig, int ncls) {
  __shared__ float red[128];
  __shared__ float emb[128];
  int t = threadIdx.x;
  float a = emb_a_sum[t] * inv_n_apig;       // mean_nodes
  float f = __uint_as_float(emb_f_bits[t]);  // max_nodes

  float vals[2] = {a, f};
  float norms[2];
#pragma unroll
  for (int which = 0; which < 2; ++which) {
    float x = vals[which];
    red[t] = x;
    __syncthreads();
    for (int o = 64; o > 0; o >>= 1) {
      if (t < o) red[t] += red[t + o];
      __syncthreads();
    }
    float mean = red[0] / 128.f;
    __syncthreads();
    float d = x - mean;
    red[t] = d * d;
    __syncthreads();
    for (int o = 64; o > 0; o >>= 1) {
      if (t < o) red[t] += red[t + o];
      __syncthreads();
    }
    float stdv = sqrtf(red[0] / 127.f);  // unbiased (ddof=1)
    __syncthreads();
    float z = d / stdv;
    red[t] = z;
    __syncthreads();
    for (int o = 64; o > 0; o >>= 1) {
      if (t < o) red[t] = fminf(red[t], red[t + o]);
      __syncthreads();
    }
    float zmin = red[0];
    __syncthreads();
    red[t] = z;
    __syncthreads();
    for (int o = 64; o > 0; o >>= 1) {
      if (t < o) red[t] = fmaxf(red[t], red[t + o]);
      __syncthreads();
    }
    float zmax = red[0];
    __syncthreads();
    norms[which] = (z - zmin) / (zmax - zmin);
  }

  // softmax over length-1 axis == 1.0 -> emb = a_norm + f_norm
  emb[t] = norms[0] + norms[1];
  __syncthreads();
  if (t < ncls) {
    float acc = b_cls[t];
    for (int k = 0; k < 128; ++k) acc = fmaf(emb[k], W_cls[k * ncls + t], acc);
    out[t] = acc;
  }
}

extern "C" void kernel_launch(void* const* d_in, const int* in_sizes, int n_in,
                              void* d_out, int out_size, void* d_ws, size_t ws_size,
                              hipStream_t stream) {
  const float* apig_feat = (const float*)d_in[0];
  const float* fcg_feat = (const float*)d_in[1];
  const float* W_a1 = (const float*)d_in[2];
  const float* b_a1 = (const float*)d_in[3];
  const float* W_a2 = (const float*)d_in[4];
  const float* b_a2 = (const float*)d_in[5];
  const float* W_f1 = (const float*)d_in[6];
  const float* b_f1 = (const float*)d_in[7];
  const float* W_f2 = (const float*)d_in[8];
  const float* b_f2 = (const float*)d_in[9];
  const float* W1 = (const float*)d_in[10];
  const float* b1 = (const float*)d_in[11];
  const float* W2 = (const float*)d_in[12];
  const float* b2 = (const float*)d_in[13];
  // d_in[14]/d_in[15] (W_attn, b_attn): dead — softmax over length-1 axis == 1.
  const float* W_cls = (const float*)d_in[16];
  const float* b_cls = (const float*)d_in[17];
  const int* a_src = (const int*)d_in[18];
  const int* a_dst = (const int*)d_in[19];
  const int* f_src = (const int*)d_in[20];
  const int* f_dst = (const int*)d_in[21];

  const int hidden = in_sizes[3];             // 128
  const int united = in_sizes[11];            // 64
  const int ncls = in_sizes[17];              // 10
  const int apig_dim = in_sizes[2] / hidden;  // 256
  const int fcg_dim = in_sizes[6] / hidden;   // 128
  const int n_a = in_sizes[0] / apig_dim;     // 50000
  const int n_f = in_sizes[1] / fcg_dim;      // 100000
  const int e_a = in_sizes[18];               // 800000
  const int e_f = in_sizes[20];               // 1600000

  // ---- workspace carve-up (all 256B aligned) ----
  char* w = (char*)d_ws;
  auto alloc = [&](size_t bytes) -> void* {
    void* p = (void*)w;
    w += (bytes + 255) & ~(size_t)255;
    return p;
  };
  float* isr_out_a = (float*)alloc((size_t)n_a * 4);
  float* isr_in_a = (float*)alloc((size_t)n_a * 4);
  float* isr_out_f = (float*)alloc((size_t)n_f * 4);
  float* isr_in_f = (float*)alloc((size_t)n_f * 4);
  int* cnt_out_a = (int*)alloc((size_t)n_a * 4);
  int* cnt_in_a = (int*)alloc((size_t)n_a * 4);
  int* offs_a = (int*)alloc((size_t)(n_a + 1) * 4);
  int* rank_a = (int*)alloc((size_t)e_a * 4);
  int* csr_a = (int*)alloc((size_t)e_a * 4);
  int* cnt_out_f = (int*)alloc((size_t)n_f * 4);
  int* cnt_in_f = (int*)alloc((size_t)n_f * 4);
  int* offs_f = (int*)alloc((size_t)(n_f + 1) * 4);
  int* rank_f = (int*)alloc((size_t)e_f * 4);
  int* csr_f = (int*)alloc((size_t)e_f * 4);
  int* blksum_a = (int*)alloc((size_t)64 * 4);
  int* blksum_f = (int*)alloc((size_t)64 * 4);
  float* A1 = (float*)alloc((size_t)n_a * hidden * 4);
  float* A2 = (float*)alloc((size_t)n_a * hidden * 4);
  float* F1 = (float*)alloc((size_t)n_f * hidden * 4);
  float* F2 = (float*)alloc((size_t)n_f * hidden * 4);
  float* a_sum = (float*)alloc((size_t)united * 4);
  float* f_sum = (float*)alloc((size_t)united * 4);
  float* emb_a = (float*)alloc((size_t)hidden * 4);
  unsigned* emb_f = (unsigned*)alloc((size_t)hidden * 4);
  (void)ws_size;
  (void)n_in;
  (void)out_size;

  const int Ba = (n_a + 4095) / 4096;  // 13
  const int Bf = (n_f + 4095) / 4096;  // 25

  // ---- degrees + rank + CSR (shared by both conv layers of each graph) ----
  hipMemsetAsync(cnt_out_a, 0, (size_t)n_a * 4, stream);
  hipMemsetAsync(cnt_in_a, 0, (size_t)n_a * 4, stream);
  hipMemsetAsync(cnt_out_f, 0, (size_t)n_f * 4, stream);
  hipMemsetAsync(cnt_in_f, 0, (size_t)n_f * 4, stream);
  count_kernel<<<(e_a + 255) / 256, 256, 0, stream>>>(a_src, a_dst, cnt_out_a, cnt_in_a, rank_a, e_a);
  count_kernel<<<(e_f + 255) / 256, 256, 0, stream>>>(f_src, f_dst, cnt_out_f, cnt_in_f, rank_f, e_f);
  isr2_kernel<<<(n_a + 255) / 256, 256, 0, stream>>>(cnt_out_a, cnt_in_a, isr_out_a, isr_in_a, n_a);
  isr2_kernel<<<(n_f + 255) / 256, 256, 0, stream>>>(cnt_out_f, cnt_in_f, isr_out_f, isr_in_f, n_f);
  // 3-phase exclusive scan of cnt_in -> offs
  blocksum_kernel<<<Ba, 256, 0, stream>>>(cnt_in_a, blksum_a, n_a);
  blocksum_kernel<<<Bf, 256, 0, stream>>>(cnt_in_f, blksum_f, n_f);
  blkscan_kernel<<<1, 64, 0, stream>>>(blksum_a, Ba);
  blkscan_kernel<<<1, 64, 0, stream>>>(blksum_f, Bf);
  offsets_kernel<<<Ba, 256, 0, stream>>>(cnt_in_a, blksum_a, offs_a, n_a);
  offsets_kernel<<<Bf, 256, 0, stream>>>(cnt_in_f, blksum_f, offs_f, n_f);
  csr_scatter_kernel<<<(e_a + 255) / 256, 256, 0, stream>>>(a_src, a_dst, offs_a, rank_a, csr_a, e_a);
  csr_scatter_kernel<<<(e_f + 255) / 256, 256, 0, stream>>>(f_src, f_dst, offs_f, rank_f, csr_f, e_f);

  dim3 blk(256);

  // ---- apig conv1: h_a1 = relu(agg((X@W_a1)*dout) * din + b_a1) ----
  gemm_kernel<<<dim3((n_a + 63) / 64, hidden / 64), blk, 0, stream>>>(
      apig_feat, W_a1, A1, n_a, hidden, apig_dim, nullptr, 0.f, isr_out_a, nullptr);
  agg_kernel<<<(n_a + 7) / 8, blk, 0, stream>>>(A1, offs_a, csr_a, isr_in_a, b_a1, A2, n_a);
  // a_enc(raw) = h_a1 @ W1 + b1  -> A1 ; a_sum = colsum(a_enc_raw)
  gemm_kernel<<<dim3((n_a + 63) / 64, united / 64), blk, 0, stream>>>(
      A2, W1, A1, n_a, united, hidden, nullptr, 0.f, nullptr, b1);
  hipMemsetAsync(a_sum, 0, (size_t)united * 4, stream);
  colsum_kernel<<<256, blk, 0, stream>>>(A1, a_sum, n_a, united);

  // ---- fcg conv1 ----
  gemm_kernel<<<dim3((n_f + 63) / 64, hidden / 64), blk, 0, stream>>>(
      fcg_feat, W_f1, F1, n_f, hidden, fcg_dim, nullptr, 0.f, isr_out_f, nullptr);
  agg_kernel<<<(n_f + 7) / 8, blk, 0, stream>>>(F1, offs_f, csr_f, isr_in_f, b_f1, F2, n_f);
  gemm_kernel<<<dim3((n_f + 63) / 64, united / 64), blk, 0, stream>>>(
      F2, W1, F1, n_f, united, hidden, nullptr, 0.f, nullptr, b1);
  hipMemsetAsync(f_sum, 0, (size_t)united * 4, stream);
  colsum_kernel<<<256, blk, 0, stream>>>(F1, f_sum, n_f, united);

  // ---- apig branch 2: a_dec = (a_enc + 0.1*f_sum)@W2 + b2; conv2; mean ----
  gemm_kernel<<<dim3((n_a + 63) / 64, hidden / 64), blk, 0, stream>>>(
      A1, W2, A2, n_a, hidden, united, f_sum, 0.1f, nullptr, b2);
  gemm_kernel<<<dim3((n_a + 63) / 64, hidden / 64), blk, 0, stream>>>(
      A2, W_a2, A1, n_a, hidden, hidden, nullptr, 0.f, isr_out_a, nullptr);
  agg_kernel<<<(n_a + 7) / 8, blk, 0, stream>>>(A1, offs_a, csr_a, isr_in_a, b_a2, A2, n_a);
  hipMemsetAsync(emb_a, 0, (size_t)hidden * 4, stream);
  colsum_kernel<<<256, blk, 0, stream>>>(A2, emb_a, n_a, hidden);

  // ---- fcg branch 2: f_dec = (f_enc + 0.1*a_sum)@W2 + b2; conv2; max ----
  gemm_kernel<<<dim3((n_f + 63) / 64, hidden / 64), blk, 0, stream>>>(
      F1, W2, F2, n_f, hidden, united, a_sum, 0.1f, nullptr, b2);
  gemm_kernel<<<dim3((n_f + 63) / 64, hidden / 64), blk, 0, stream>>>(
      F2, W_f2, F1, n_f, hidden, hidden, nullptr, 0.f, isr_out_f, nullptr);
  agg_kernel<<<(n_f + 7) / 8, blk, 0, stream>>>(F1, offs_f, csr_f, isr_in_f, b_f2, F2, n_f);
  hipMemsetAsync(emb_f, 0, (size_t)hidden * 4, stream);
  colmax_kernel<<<256, blk, 0, stream>>>(F2, emb_f, n_f, hidden);

  // ---- head ----
  final_kernel<<<1, 128, 0, stream>>>(emb_a, emb_f, W_cls, b_cls, (float*)d_out,
                                      1.0f / (float)n_a, ncls);
}

// Round 5
// 1101.353 us; speedup vs baseline: 1.5424x; 1.1927x over previous
//
#include <hip/hip_runtime.h>
#include <math.h>

// ---------------------------------------------------------------------------
// MultiGraphClassifier on MI355X.
// Pipeline: 2x GraphConv per graph + cross-graph fusion + tiny head.
// Strategy: CSR build per call (rank-capturing counting sort, atomic-free
// scatter), gather-side aggregation over bf16 tables, bf16-MFMA GEMMs with
// fp32 accumulate and fused degree-scale / bias / fusion-add epilogues.
// Note: softmax over a length-1 axis == 1.0, so emb = norm(a) + norm(f).
// R1: 3-phase scan (was 2x234us single-block).
// R3: atomic-free scatter via rank captured in count (105MB -> ~10MB writes).
// R4: fp32 VALU GEMMs -> bf16 MFMA (16x16x32); gathered tables bf16 (halves
//     agg traffic). Reductions/intermediates stay fp32.
// ---------------------------------------------------------------------------

typedef __attribute__((ext_vector_type(8))) short bf16x8;
typedef __attribute__((ext_vector_type(4))) float f32x4;

static __device__ inline unsigned short f2bf(float f) {
  unsigned u = __float_as_uint(f);
  unsigned r = (u + 0x7fff + ((u >> 16) & 1)) >> 16;  // RNE
  return (unsigned short)r;
}
static __device__ inline float bf2f(unsigned short h) {
  return __uint_as_float(((unsigned)h) << 16);
}

__global__ void count_kernel(const int* __restrict__ src, const int* __restrict__ dst,
                             int* __restrict__ cnt_out, int* __restrict__ cnt_in,
                             int* __restrict__ rank, int E) {
  int e = blockIdx.x * blockDim.x + threadIdx.x;
  if (e < E) {
    atomicAdd(&cnt_out[src[e]], 1);
    rank[e] = atomicAdd(&cnt_in[dst[e]], 1);  // stable slot within dst bucket
  }
}

__global__ void isr2_kernel(const int* __restrict__ cnt_out, const int* __restrict__ cnt_in,
                            float* __restrict__ isr_out, float* __restrict__ isr_in, int n) {
  int i = blockIdx.x * blockDim.x + threadIdx.x;
  if (i < n) {
    int co = cnt_out[i];
    if (co < 1) co = 1;
    isr_out[i] = 1.0f / sqrtf((float)co);
    int ci = cnt_in[i];
    if (ci < 1) ci = 1;
    isr_in[i] = 1.0f / sqrtf((float)ci);
  }
}

// ---- 3-phase exclusive scan over cnt[n], tile = 4096 ----
__global__ __launch_bounds__(256) void blocksum_kernel(const int* __restrict__ cnt,
                                                       int* __restrict__ blksum, int n) {
  __shared__ int red[256];
  int base = blockIdx.x * 4096 + threadIdx.x * 16;
  int s = 0;
#pragma unroll
  for (int j = 0; j < 16; ++j) {
    int idx = base + j;
    if (idx < n) s += cnt[idx];
  }
  red[threadIdx.x] = s;
  __syncthreads();
  for (int o = 128; o > 0; o >>= 1) {
    if (threadIdx.x < o) red[threadIdx.x] += red[threadIdx.x + o];
    __syncthreads();
  }
  if (threadIdx.x == 0) blksum[blockIdx.x] = red[0];
}

__global__ __launch_bounds__(64) void blkscan_kernel(int* __restrict__ blksum, int B) {
  int t = threadIdx.x;
  int v = (t < B) ? blksum[t] : 0;
  int inc = v;
#pragma unroll
  for (int o = 1; o < 64; o <<= 1) {
    int u = __shfl_up(inc, o, 64);
    if (t >= o) inc += u;
  }
  if (t < B) blksum[t] = inc - v;  // exclusive
}

__global__ __launch_bounds__(256) void offsets_kernel(const int* __restrict__ cnt,
                                                      const int* __restrict__ blkoffs,
                                                      int* __restrict__ offs, int n) {
  __shared__ int part[256];
  int base = blockIdx.x * 4096 + threadIdx.x * 16;
  int c[16];
  int s = 0;
#pragma unroll
  for (int j = 0; j < 16; ++j) {
    int idx = base + j;
    c[j] = (idx < n) ? cnt[idx] : 0;
    s += c[j];
  }
  part[threadIdx.x] = s;
  __syncthreads();
  for (int o = 1; o < 256; o <<= 1) {
    int v = (threadIdx.x >= o) ? part[threadIdx.x - o] : 0;
    __syncthreads();
    part[threadIdx.x] += v;
    __syncthreads();
  }
  int run = blkoffs[blockIdx.x] + part[threadIdx.x] - s;
#pragma unroll
  for (int j = 0; j < 16; ++j) {
    int idx = base + j;
    if (idx < n) {
      offs[idx] = run;
      run += c[j];
      if (idx == n - 1) offs[n] = run;
    }
  }
}

__global__ void csr_scatter_kernel(const int* __restrict__ src, const int* __restrict__ dst,
                                   const int* __restrict__ offs, const int* __restrict__ rank,
                                   int* __restrict__ csr, int E) {
  int e = blockIdx.x * blockDim.x + threadIdx.x;
  if (e < E) {
    csr[offs[dst[e]] + rank[e]] = src[e];
  }
}

// ---------------------------------------------------------------------------
// bf16-MFMA GEMM: C[M,N] = epi( (A[M,K](+s*add_vec[K])) @ B[K,N] )
// A,B fp32 in global, cast bf16 in LDS staging. fp32 accumulate (MFMA).
// epi: *rowscale[M]?  +bias[N]?  out bf16 or fp32.
// Requires N%64==0, K%64==0. Tile 64x64, 256 thr = 4 waves x (16 rows x 64).
// LDS rows padded to 72 shorts: fragment b128 reads are 2-way-bank (free).
// ---------------------------------------------------------------------------
#define LDT 72
__global__ __launch_bounds__(256) void gemm_mfma_kernel(
    const float* __restrict__ A, const float* __restrict__ B, void* __restrict__ C,
    int M, int N, int K,
    const float* __restrict__ add_vec, float add_scale,
    const float* __restrict__ rowscale, const float* __restrict__ bias, int out_bf16) {
  __shared__ __align__(16) short As[64 * LDT];  // [m][k]
  __shared__ __align__(16) short Bs[64 * LDT];  // [n][k] (transposed)
  const int m0 = blockIdx.x * 64, n0 = blockIdx.y * 64;
  const int tid = threadIdx.x;
  const int lane = tid & 63, w = tid >> 6;
  const int q = lane >> 4, l16 = lane & 15;
  const int srow = tid >> 2, schunk = (tid & 3) * 16;
  f32x4 acc[4] = {};
  for (int k0 = 0; k0 < K; k0 += 64) {
    // stage A row srow, k chunk [schunk, schunk+16)
    {
      int m = m0 + srow;
      float tmp[16];
      if (m < M) {
        const float* s = A + (size_t)m * K + k0 + schunk;
#pragma unroll
        for (int i = 0; i < 16; i += 4) {
          float4 v = *reinterpret_cast<const float4*>(s + i);
          tmp[i] = v.x; tmp[i + 1] = v.y; tmp[i + 2] = v.z; tmp[i + 3] = v.w;
        }
        if (add_vec) {
#pragma unroll
          for (int i = 0; i < 16; ++i) tmp[i] += add_scale * add_vec[k0 + schunk + i];
        }
      } else {
#pragma unroll
        for (int i = 0; i < 16; ++i) tmp[i] = 0.f;
      }
#pragma unroll
      for (int i = 0; i < 16; ++i) As[srow * LDT + schunk + i] = (short)f2bf(tmp[i]);
    }
    // stage B transposed: Bs[n][k]=B[k0+srow][n0+schunk+i]
    {
      const float* s = B + (size_t)(k0 + srow) * N + n0 + schunk;
#pragma unroll
      for (int i = 0; i < 16; i += 4) {
        float4 v = *reinterpret_cast<const float4*>(s + i);
        Bs[(schunk + i + 0) * LDT + srow] = (short)f2bf(v.x);
        Bs[(schunk + i + 1) * LDT + srow] = (short)f2bf(v.y);
        Bs[(schunk + i + 2) * LDT + srow] = (short)f2bf(v.z);
        Bs[(schunk + i + 3) * LDT + srow] = (short)f2bf(v.w);
      }
    }
    __syncthreads();
#pragma unroll
    for (int kk = 0; kk < 2; ++kk) {
      bf16x8 af = *reinterpret_cast<const bf16x8*>(&As[(w * 16 + l16) * LDT + kk * 32 + q * 8]);
#pragma unroll
      for (int nt = 0; nt < 4; ++nt) {
        bf16x8 bf = *reinterpret_cast<const bf16x8*>(&Bs[(nt * 16 + l16) * LDT + kk * 32 + q * 8]);
        acc[nt] = __builtin_amdgcn_mfma_f32_16x16x32_bf16(af, bf, acc[nt], 0, 0, 0);
      }
    }
    __syncthreads();
  }
#pragma unroll
  for (int nt = 0; nt < 4; ++nt) {
    int gcol = n0 + nt * 16 + l16;
    float bv = bias ? bias[gcol] : 0.f;
#pragma unroll
    for (int r = 0; r < 4; ++r) {
      int grow = m0 + w * 16 + q * 4 + r;
      if (grow < M) {
        float v = acc[nt][r];
        if (rowscale) v *= rowscale[grow];
        v += bv;
        if (out_bf16)
          ((unsigned short*)C)[(size_t)grow * N + gcol] = f2bf(v);
        else
          ((float*)C)[(size_t)grow * N + gcol] = v;
      }
    }
  }
}

// H[node] = relu( (sum_{e in CSR[node]} XW_bf16[src(e)]) * isr_in[node] + b )
// 32 threads per node (128 ch, 4/lane), 8 nodes per 256-thread block.
__global__ __launch_bounds__(256) void agg_kernel(
    const unsigned short* __restrict__ XW, const int* __restrict__ offs,
    const int* __restrict__ csr, const float* __restrict__ isr_in,
    const float* __restrict__ bias, float* __restrict__ H, int n) {
  int lane = threadIdx.x & 31;
  int node = blockIdx.x * 8 + (threadIdx.x >> 5);
  if (node >= n) return;
  int e0 = offs[node], e1 = offs[node + 1];
  float4 acc = make_float4(0.f, 0.f, 0.f, 0.f);
  for (int e = e0; e < e1; ++e) {
    int s = csr[e];
    ushort4 v = *reinterpret_cast<const ushort4*>(&XW[(size_t)s * 128 + lane * 4]);
    acc.x += bf2f(v.x);
    acc.y += bf2f(v.y);
    acc.z += bf2f(v.z);
    acc.w += bf2f(v.w);
  }
  float sc = isr_in[node];
  float4 b = *reinterpret_cast<const float4*>(&bias[lane * 4]);
  float4 o;
  o.x = fmaxf(fmaf(acc.x, sc, b.x), 0.f);
  o.y = fmaxf(fmaf(acc.y, sc, b.y), 0.f);
  o.z = fmaxf(fmaf(acc.z, sc, b.z), 0.f);
  o.w = fmaxf(fmaf(acc.w, sc, b.w), 0.f);
  *reinterpret_cast<float4*>(&H[(size_t)node * 128 + lane * 4]) = o;
}

// out[col] += column sums of X[n, ncol]; out pre-zeroed. ncol | 256.
__global__ __launch_bounds__(256) void colsum_kernel(const float* __restrict__ X,
                                                     float* __restrict__ out, int n, int ncol) {
  __shared__ float s[256];
  int col = threadIdx.x % ncol;
  int rpb = 256 / ncol;
  int rb = threadIdx.x / ncol;
  float acc = 0.f;
  for (int r = blockIdx.x * rpb + rb; r < n; r += gridDim.x * rpb)
    acc += X[(size_t)r * ncol + col];
  s[threadIdx.x] = acc;
  __syncthreads();
  if (threadIdx.x < ncol) {
    float v = 0.f;
    for (int i = 0; i < rpb; ++i) v += s[threadIdx.x + i * ncol];
    atomicAdd(&out[col], v);
  }
}

// out[col] = max over rows (X >= 0 relu output; out pre-zeroed).
__global__ __launch_bounds__(256) void colmax_kernel(const float* __restrict__ X,
                                                     unsigned* __restrict__ out, int n, int ncol) {
  __shared__ float s[256];
  int col = threadIdx.x % ncol;
  int rpb = 256 / ncol;
  int rb = threadIdx.x / ncol;
  float acc = 0.f;
  for (int r = blockIdx.x * rpb + rb; r < n; r += gridDim.x * rpb)
    acc = fmaxf(acc, X[(size_t)r * ncol + col]);
  s[threadIdx.x] = acc;
  __syncthreads();
  if (threadIdx.x < ncol) {
    float v = s[threadIdx.x];
    for (int i = 1; i < rpb; ++i) v = fmaxf(v, s[threadIdx.x + i * ncol]);
    atomicMax(&out[col], __float_as_uint(v));
  }
}

// norm_embed(a) + norm_embed(f) then @ W_cls + b_cls. Single block of 128.
__global__ __launch_bounds__(128) void final_kernel(
    const float* __restrict__ emb_a_sum, const unsigned* __restrict__ emb_f_bits,
    const float* __restrict__ W_cls, const float* __restrict__ b_cls,
    float* __restrict__ out, float inv_n_apig, int ncls) {
  __shared__ float red[128];
  __shared__ float emb[128];
  int t = threadIdx.x;
  float a = emb_a_sum[t] * inv_n_apig;
  float f = __uint_as_float(emb_f_bits[t]);

  float vals[2] = {a, f};
  float norms[2];
#pragma unroll
  for (int which = 0; which < 2; ++which) {
    float x = vals[which];
    red[t] = x;
    __syncthreads();
    for (int o = 64; o > 0; o >>= 1) {
      if (t < o) red[t] += red[t + o];
      __syncthreads();
    }
    float mean = red[0] / 128.f;
    __syncthreads();
    float d = x - mean;
    red[t] = d * d;
    __syncthreads();
    for (int o = 64; o > 0; o >>= 1) {
      if (t < o) red[t] += red[t + o];
      __syncthreads();
    }
    float stdv = sqrtf(red[0] / 127.f);  // ddof=1
    __syncthreads();
    float z = d / stdv;
    red[t] = z;
    __syncthreads();
    for (int o = 64; o > 0; o >>= 1) {
      if (t < o) red[t] = fminf(red[t], red[t + o]);
      __syncthreads();
    }
    float zmin = red[0];
    __syncthreads();
    red[t] = z;
    __syncthreads();
    for (int o = 64; o > 0; o >>= 1) {
      if (t < o) red[t] = fmaxf(red[t], red[t + o]);
      __syncthreads();
    }
    float zmax = red[0];
    __syncthreads();
    norms[which] = (z - zmin) / (zmax - zmin);
  }

  emb[t] = norms[0] + norms[1];
  __syncthreads();
  if (t < ncls) {
    float acc = b_cls[t];
    for (int k = 0; k < 128; ++k) acc = fmaf(emb[k], W_cls[k * ncls + t], acc);
    out[t] = acc;
  }
}

extern "C" void kernel_launch(void* const* d_in, const int* in_sizes, int n_in,
                              void* d_out, int out_size, void* d_ws, size_t ws_size,
                              hipStream_t stream) {
  const float* apig_feat = (const float*)d_in[0];
  const float* fcg_feat = (const float*)d_in[1];
  const float* W_a1 = (const float*)d_in[2];
  const float* b_a1 = (const float*)d_in[3];
  const float* W_a2 = (const float*)d_in[4];
  const float* b_a2 = (const float*)d_in[5];
  const float* W_f1 = (const float*)d_in[6];
  const float* b_f1 = (const float*)d_in[7];
  const float* W_f2 = (const float*)d_in[8];
  const float* b_f2 = (const float*)d_in[9];
  const float* W1 = (const float*)d_in[10];
  const float* b1 = (const float*)d_in[11];
  const float* W2 = (const float*)d_in[12];
  const float* b2 = (const float*)d_in[13];
  // d_in[14]/d_in[15] (W_attn, b_attn): dead — softmax over length-1 axis == 1.
  const float* W_cls = (const float*)d_in[16];
  const float* b_cls = (const float*)d_in[17];
  const int* a_src = (const int*)d_in[18];
  const int* a_dst = (const int*)d_in[19];
  const int* f_src = (const int*)d_in[20];
  const int* f_dst = (const int*)d_in[21];

  const int hidden = in_sizes[3];             // 128
  const int united = in_sizes[11];            // 64
  const int ncls = in_sizes[17];              // 10
  const int apig_dim = in_sizes[2] / hidden;  // 256
  const int fcg_dim = in_sizes[6] / hidden;   // 128
  const int n_a = in_sizes[0] / apig_dim;     // 50000
  const int n_f = in_sizes[1] / fcg_dim;      // 100000
  const int e_a = in_sizes[18];               // 800000
  const int e_f = in_sizes[20];               // 1600000

  // ---- workspace carve-up (all 256B aligned) ----
  char* w = (char*)d_ws;
  auto alloc = [&](size_t bytes) -> void* {
    void* p = (void*)w;
    w += (bytes + 255) & ~(size_t)255;
    return p;
  };
  float* isr_out_a = (float*)alloc((size_t)n_a * 4);
  float* isr_in_a = (float*)alloc((size_t)n_a * 4);
  float* isr_out_f = (float*)alloc((size_t)n_f * 4);
  float* isr_in_f = (float*)alloc((size_t)n_f * 4);
  int* cnt_out_a = (int*)alloc((size_t)n_a * 4);
  int* cnt_in_a = (int*)alloc((size_t)n_a * 4);
  int* offs_a = (int*)alloc((size_t)(n_a + 1) * 4);
  int* rank_a = (int*)alloc((size_t)e_a * 4);
  int* csr_a = (int*)alloc((size_t)e_a * 4);
  int* cnt_out_f = (int*)alloc((size_t)n_f * 4);
  int* cnt_in_f = (int*)alloc((size_t)n_f * 4);
  int* offs_f = (int*)alloc((size_t)(n_f + 1) * 4);
  int* rank_f = (int*)alloc((size_t)e_f * 4);
  int* csr_f = (int*)alloc((size_t)e_f * 4);
  int* blksum_a = (int*)alloc((size_t)64 * 4);
  int* blksum_f = (int*)alloc((size_t)64 * 4);
  unsigned short* G_a = (unsigned short*)alloc((size_t)n_a * hidden * 2);  // bf16 gather table
  float* H_a = (float*)alloc((size_t)n_a * hidden * 4);                    // h1 / a_dec / h2
  float* E_a = (float*)alloc((size_t)n_a * united * 4);                    // enc raw
  unsigned short* G_f = (unsigned short*)alloc((size_t)n_f * hidden * 2);
  float* H_f = (float*)alloc((size_t)n_f * hidden * 4);
  float* E_f = (float*)alloc((size_t)n_f * united * 4);
  float* a_sum = (float*)alloc((size_t)united * 4);
  float* f_sum = (float*)alloc((size_t)united * 4);
  float* emb_a = (float*)alloc((size_t)hidden * 4);
  unsigned* emb_f = (unsigned*)alloc((size_t)hidden * 4);
  (void)ws_size;
  (void)n_in;
  (void)out_size;

  const int Ba = (n_a + 4095) / 4096;
  const int Bf = (n_f + 4095) / 4096;

  // ---- degrees + rank + CSR ----
  hipMemsetAsync(cnt_out_a, 0, (size_t)n_a * 4, stream);
  hipMemsetAsync(cnt_in_a, 0, (size_t)n_a * 4, stream);
  hipMemsetAsync(cnt_out_f, 0, (size_t)n_f * 4, stream);
  hipMemsetAsync(cnt_in_f, 0, (size_t)n_f * 4, stream);
  count_kernel<<<(e_a + 255) / 256, 256, 0, stream>>>(a_src, a_dst, cnt_out_a, cnt_in_a, rank_a, e_a);
  count_kernel<<<(e_f + 255) / 256, 256, 0, stream>>>(f_src, f_dst, cnt_out_f, cnt_in_f, rank_f, e_f);
  isr2_kernel<<<(n_a + 255) / 256, 256, 0, stream>>>(cnt_out_a, cnt_in_a, isr_out_a, isr_in_a, n_a);
  isr2_kernel<<<(n_f + 255) / 256, 256, 0, stream>>>(cnt_out_f, cnt_in_f, isr_out_f, isr_in_f, n_f);
  blocksum_kernel<<<Ba, 256, 0, stream>>>(cnt_in_a, blksum_a, n_a);
  blocksum_kernel<<<Bf, 256, 0, stream>>>(cnt_in_f, blksum_f, n_f);
  blkscan_kernel<<<1, 64, 0, stream>>>(blksum_a, Ba);
  blkscan_kernel<<<1, 64, 0, stream>>>(blksum_f, Bf);
  offsets_kernel<<<Ba, 256, 0, stream>>>(cnt_in_a, blksum_a, offs_a, n_a);
  offsets_kernel<<<Bf, 256, 0, stream>>>(cnt_in_f, blksum_f, offs_f, n_f);
  csr_scatter_kernel<<<(e_a + 255) / 256, 256, 0, stream>>>(a_src, a_dst, offs_a, rank_a, csr_a, e_a);
  csr_scatter_kernel<<<(e_f + 255) / 256, 256, 0, stream>>>(f_src, f_dst, offs_f, rank_f, csr_f, e_f);

  dim3 blk(256);
  const int ga = (n_a + 63) / 64, gf = (n_f + 63) / 64;

  // ---- apig conv1 + enc ----
  gemm_mfma_kernel<<<dim3(ga, hidden / 64), blk, 0, stream>>>(
      apig_feat, W_a1, G_a, n_a, hidden, apig_dim, nullptr, 0.f, isr_out_a, nullptr, 1);
  agg_kernel<<<(n_a + 7) / 8, blk, 0, stream>>>(G_a, offs_a, csr_a, isr_in_a, b_a1, H_a, n_a);
  gemm_mfma_kernel<<<dim3(ga, united / 64), blk, 0, stream>>>(
      H_a, W1, E_a, n_a, united, hidden, nullptr, 0.f, nullptr, b1, 0);
  hipMemsetAsync(a_sum, 0, (size_t)united * 4, stream);
  colsum_kernel<<<256, blk, 0, stream>>>(E_a, a_sum, n_a, united);

  // ---- fcg conv1 + enc ----
  gemm_mfma_kernel<<<dim3(gf, hidden / 64), blk, 0, stream>>>(
      fcg_feat, W_f1, G_f, n_f, hidden, fcg_dim, nullptr, 0.f, isr_out_f, nullptr, 1);
  agg_kernel<<<(n_f + 7) / 8, blk, 0, stream>>>(G_f, offs_f, csr_f, isr_in_f, b_f1, H_f, n_f);
  gemm_mfma_kernel<<<dim3(gf, united / 64), blk, 0, stream>>>(
      H_f, W1, E_f, n_f, united, hidden, nullptr, 0.f, nullptr, b1, 0);
  hipMemsetAsync(f_sum, 0, (size_t)united * 4, stream);
  colsum_kernel<<<256, blk, 0, stream>>>(E_f, f_sum, n_f, united);

  // ---- apig dec + conv2 + mean ----
  gemm_mfma_kernel<<<dim3(ga, hidden / 64), blk, 0, stream>>>(
      E_a, W2, H_a, n_a, hidden, united, f_sum, 0.1f, nullptr, b2, 0);  // a_dec (h1 dead)
  gemm_mfma_kernel<<<dim3(ga, hidden / 64), blk, 0, stream>>>(
      H_a, W_a2, G_a, n_a, hidden, hidden, nullptr, 0.f, isr_out_a, nullptr, 1);
  agg_kernel<<<(n_a + 7) / 8, blk, 0, stream>>>(G_a, offs_a, csr_a, isr_in_a, b_a2, H_a, n_a);
  hipMemsetAsync(emb_a, 0, (size_t)hidden * 4, stream);
  colsum_kernel<<<256, blk, 0, stream>>>(H_a, emb_a, n_a, hidden);

  // ---- fcg dec + conv2 + max ----
  gemm_mfma_kernel<<<dim3(gf, hidden / 64), blk, 0, stream>>>(
      E_f, W2, H_f, n_f, hidden, united, a_sum, 0.1f, nullptr, b2, 0);  // f_dec
  gemm_mfma_kernel<<<dim3(gf, hidden / 64), blk, 0, stream>>>(
      H_f, W_f2, G_f, n_f, hidden, hidden, nullptr, 0.f, isr_out_f, nullptr, 1);
  agg_kernel<<<(n_f + 7) / 8, blk, 0, stream>>>(G_f, offs_f, csr_f, isr_in_f, b_f2, H_f, n_f);
  hipMemsetAsync(emb_f, 0, (size_t)hidden * 4, stream);
  colmax_kernel<<<256, blk, 0, stream>>>(H_f, emb_f, n_f, hidden);

  // ---- head ----
  final_kernel<<<1, 128, 0, stream>>>(emb_a, emb_f, W_cls, b_cls, (float*)d_out,
                                      1.0f / (float)n_a, ncls);
}

// Round 6
// 947.284 us; speedup vs baseline: 1.7932x; 1.1626x over previous
//
#include <hip/hip_runtime.h>
#include <math.h>

// ---------------------------------------------------------------------------
// MultiGraphClassifier on MI355X.
// Pipeline: 2x GraphConv per graph + cross-graph fusion + tiny head.
// Strategy: CSR build per call (rank-capturing counting sort, atomic-free
// scatter), gather-side aggregation over bf16 tables, bf16-MFMA GEMMs with
// fp32 accumulate and fused degree-scale / bias / fusion-add epilogues.
// Note: softmax over a length-1 axis == 1.0, so emb = norm(a) + norm(f).
// R1: 3-phase scan (was 2x234us single-block).
// R3: atomic-free scatter via rank captured in count (105MB -> ~10MB writes).
// R4: bf16 MFMA GEMMs; bf16 gather tables. 1314 -> 1101us.
// R5: count is at its atomic floor (2 dev-scope atomics/edge, ~50ns each;
//     bins~items defeats privatization). This round: 4-wide unrolled agg
//     gather (4 loads in flight vs 1) + dispatch fusion (37 -> 24 launches).
// ---------------------------------------------------------------------------

typedef __attribute__((ext_vector_type(8))) short bf16x8;
typedef __attribute__((ext_vector_type(4))) float f32x4;

static __device__ inline unsigned short f2bf(float f) {
  unsigned u = __float_as_uint(f);
  unsigned r = (u + 0x7fff + ((u >> 16) & 1)) >> 16;  // RNE
  return (unsigned short)r;
}
static __device__ inline float bf2f(unsigned short h) {
  return __uint_as_float(((unsigned)h) << 16);
}

// Zero all counter/accumulator buffers in one dispatch.
__global__ void zero_kernel(int* __restrict__ a0, int* __restrict__ a1, int na,
                            int* __restrict__ f0, int* __restrict__ f1, int nf,
                            float* __restrict__ s0, float* __restrict__ s1, int ns,
                            float* __restrict__ ea, unsigned* __restrict__ ef, int ne) {
  int i = blockIdx.x * blockDim.x + threadIdx.x;
  if (i < na) { a0[i] = 0; a1[i] = 0; }
  if (i < nf) { f0[i] = 0; f1[i] = 0; }
  if (i < ns) { s0[i] = 0.f; s1[i] = 0.f; }
  if (i < ne) { ea[i] = 0.f; ef[i] = 0u; }
}

// Both graphs' degree histograms + rank capture in one dispatch.
__global__ void count2_kernel(const int* __restrict__ a_src, const int* __restrict__ a_dst,
                              int* __restrict__ co_a, int* __restrict__ ci_a,
                              int* __restrict__ rank_a, int e_a,
                              const int* __restrict__ f_src, const int* __restrict__ f_dst,
                              int* __restrict__ co_f, int* __restrict__ ci_f,
                              int* __restrict__ rank_f, int e_f) {
  int e = blockIdx.x * blockDim.x + threadIdx.x;
  if (e < e_a) {
    atomicAdd(&co_a[a_src[e]], 1);
    rank_a[e] = atomicAdd(&ci_a[a_dst[e]], 1);
  } else if (e - e_a < e_f) {
    int i = e - e_a;
    atomicAdd(&co_f[f_src[i]], 1);
    rank_f[i] = atomicAdd(&ci_f[f_dst[i]], 1);
  }
}

// isr = 1/sqrt(clip(deg,1)) for all four degree arrays in one dispatch.
__global__ void isr4_kernel(const int* __restrict__ co_a, const int* __restrict__ ci_a,
                            float* __restrict__ io_a, float* __restrict__ ii_a, int n_a,
                            const int* __restrict__ co_f, const int* __restrict__ ci_f,
                            float* __restrict__ io_f, float* __restrict__ ii_f, int n_f) {
  int i = blockIdx.x * blockDim.x + threadIdx.x;
  if (i < n_a) {
    int c = co_a[i]; if (c < 1) c = 1;
    io_a[i] = 1.0f / sqrtf((float)c);
    c = ci_a[i]; if (c < 1) c = 1;
    ii_a[i] = 1.0f / sqrtf((float)c);
  }
  if (i < n_f) {
    int c = co_f[i]; if (c < 1) c = 1;
    io_f[i] = 1.0f / sqrtf((float)c);
    c = ci_f[i]; if (c < 1) c = 1;
    ii_f[i] = 1.0f / sqrtf((float)c);
  }
}

// ---- 3-phase exclusive scan, both graphs per dispatch; tile = 4096 ----
// blksum layout: [0,Ba) graph a, [Ba,Ba+Bf) graph f.
__global__ __launch_bounds__(256) void blocksum2_kernel(
    const int* __restrict__ cnt_a, int n_a, const int* __restrict__ cnt_f, int n_f,
    int* __restrict__ blksum, int Ba) {
  __shared__ int red[256];
  bool isA = (int)blockIdx.x < Ba;
  const int* cnt = isA ? cnt_a : cnt_f;
  int n = isA ? n_a : n_f;
  int b = isA ? blockIdx.x : blockIdx.x - Ba;
  int base = b * 4096 + threadIdx.x * 16;
  int s = 0;
#pragma unroll
  for (int j = 0; j < 16; ++j) {
    int idx = base + j;
    if (idx < n) s += cnt[idx];
  }
  red[threadIdx.x] = s;
  __syncthreads();
  for (int o = 128; o > 0; o >>= 1) {
    if (threadIdx.x < o) red[threadIdx.x] += red[threadIdx.x + o];
    __syncthreads();
  }
  if (threadIdx.x == 0) blksum[blockIdx.x] = red[0];
}

// One wave scans both segments sequentially (B <= 64 each), in place.
__global__ __launch_bounds__(64) void blkscan2_kernel(int* __restrict__ blksum, int Ba, int Bf) {
  int t = threadIdx.x;
#pragma unroll
  for (int seg = 0; seg < 2; ++seg) {
    int off = seg ? Ba : 0;
    int B = seg ? Bf : Ba;
    int v = (t < B) ? blksum[off + t] : 0;
    int inc = v;
#pragma unroll
    for (int o = 1; o < 64; o <<= 1) {
      int u = __shfl_up(inc, o, 64);
      if (t >= o) inc += u;
    }
    if (t < B) blksum[off + t] = inc - v;  // exclusive
  }
}

__global__ __launch_bounds__(256) void offsets2_kernel(
    const int* __restrict__ cnt_a, int* __restrict__ offs_a, int n_a,
    const int* __restrict__ cnt_f, int* __restrict__ offs_f, int n_f,
    const int* __restrict__ blkoffs, int Ba) {
  __shared__ int part[256];
  bool isA = (int)blockIdx.x < Ba;
  const int* cnt = isA ? cnt_a : cnt_f;
  int* offs = isA ? offs_a : offs_f;
  int n = isA ? n_a : n_f;
  int b = isA ? blockIdx.x : blockIdx.x - Ba;
  int base = b * 4096 + threadIdx.x * 16;
  int c[16];
  int s = 0;
#pragma unroll
  for (int j = 0; j < 16; ++j) {
    int idx = base + j;
    c[j] = (idx < n) ? cnt[idx] : 0;
    s += c[j];
  }
  part[threadIdx.x] = s;
  __syncthreads();
  for (int o = 1; o < 256; o <<= 1) {
    int v = (threadIdx.x >= o) ? part[threadIdx.x - o] : 0;
    __syncthreads();
    part[threadIdx.x] += v;
    __syncthreads();
  }
  int run = blkoffs[blockIdx.x] + part[threadIdx.x] - s;
#pragma unroll
  for (int j = 0; j < 16; ++j) {
    int idx = base + j;
    if (idx < n) {
      offs[idx] = run;
      run += c[j];
      if (idx == n - 1) offs[n] = run;
    }
  }
}

// Atomic-free scatter for both graphs: slot = offs[dst] + rank.
__global__ void scatter2_kernel(const int* __restrict__ a_src, const int* __restrict__ a_dst,
                                const int* __restrict__ offs_a, const int* __restrict__ rank_a,
                                int* __restrict__ csr_a, int e_a,
                                const int* __restrict__ f_src, const int* __restrict__ f_dst,
                                const int* __restrict__ offs_f, const int* __restrict__ rank_f,
                                int* __restrict__ csr_f, int e_f) {
  int e = blockIdx.x * blockDim.x + threadIdx.x;
  if (e < e_a) {
    csr_a[offs_a[a_dst[e]] + rank_a[e]] = a_src[e];
  } else if (e - e_a < e_f) {
    int i = e - e_a;
    csr_f[offs_f[f_dst[i]] + rank_f[i]] = f_src[i];
  }
}

// ---------------------------------------------------------------------------
// bf16-MFMA GEMM: C[M,N] = epi( (A[M,K](+s*add_vec[K])) @ B[K,N] )
// A,B fp32 in global, cast bf16 in LDS staging. fp32 accumulate (MFMA).
// epi: *rowscale[M]?  +bias[N]?  out bf16 or fp32.
// Requires N%64==0, K%64==0. Tile 64x64, 256 thr = 4 waves x (16 rows x 64).
// ---------------------------------------------------------------------------
#define LDT 72
__global__ __launch_bounds__(256) void gemm_mfma_kernel(
    const float* __restrict__ A, const float* __restrict__ B, void* __restrict__ C,
    int M, int N, int K,
    const float* __restrict__ add_vec, float add_scale,
    const float* __restrict__ rowscale, const float* __restrict__ bias, int out_bf16) {
  __shared__ __align__(16) short As[64 * LDT];  // [m][k]
  __shared__ __align__(16) short Bs[64 * LDT];  // [n][k] (transposed)
  const int m0 = blockIdx.x * 64, n0 = blockIdx.y * 64;
  const int tid = threadIdx.x;
  const int lane = tid & 63, w = tid >> 6;
  const int q = lane >> 4, l16 = lane & 15;
  const int srow = tid >> 2, schunk = (tid & 3) * 16;
  f32x4 acc[4] = {};
  for (int k0 = 0; k0 < K; k0 += 64) {
    {
      int m = m0 + srow;
      float tmp[16];
      if (m < M) {
        const float* s = A + (size_t)m * K + k0 + schunk;
#pragma unroll
        for (int i = 0; i < 16; i += 4) {
          float4 v = *reinterpret_cast<const float4*>(s + i);
          tmp[i] = v.x; tmp[i + 1] = v.y; tmp[i + 2] = v.z; tmp[i + 3] = v.w;
        }
        if (add_vec) {
#pragma unroll
          for (int i = 0; i < 16; ++i) tmp[i] += add_scale * add_vec[k0 + schunk + i];
        }
      } else {
#pragma unroll
        for (int i = 0; i < 16; ++i) tmp[i] = 0.f;
      }
#pragma unroll
      for (int i = 0; i < 16; ++i) As[srow * LDT + schunk + i] = (short)f2bf(tmp[i]);
    }
    {
      const float* s = B + (size_t)(k0 + srow) * N + n0 + schunk;
#pragma unroll
      for (int i = 0; i < 16; i += 4) {
        float4 v = *reinterpret_cast<const float4*>(s + i);
        Bs[(schunk + i + 0) * LDT + srow] = (short)f2bf(v.x);
        Bs[(schunk + i + 1) * LDT + srow] = (short)f2bf(v.y);
        Bs[(schunk + i + 2) * LDT + srow] = (short)f2bf(v.z);
        Bs[(schunk + i + 3) * LDT + srow] = (short)f2bf(v.w);
      }
    }
    __syncthreads();
#pragma unroll
    for (int kk = 0; kk < 2; ++kk) {
      bf16x8 af = *reinterpret_cast<const bf16x8*>(&As[(w * 16 + l16) * LDT + kk * 32 + q * 8]);
#pragma unroll
      for (int nt = 0; nt < 4; ++nt) {
        bf16x8 bf = *reinterpret_cast<const bf16x8*>(&Bs[(nt * 16 + l16) * LDT + kk * 32 + q * 8]);
        acc[nt] = __builtin_amdgcn_mfma_f32_16x16x32_bf16(af, bf, acc[nt], 0, 0, 0);
      }
    }
    __syncthreads();
  }
#pragma unroll
  for (int nt = 0; nt < 4; ++nt) {
    int gcol = n0 + nt * 16 + l16;
    float bv = bias ? bias[gcol] : 0.f;
#pragma unroll
    for (int r = 0; r < 4; ++r) {
      int grow = m0 + w * 16 + q * 4 + r;
      if (grow < M) {
        float v = acc[nt][r];
        if (rowscale) v *= rowscale[grow];
        v += bv;
        if (out_bf16)
          ((unsigned short*)C)[(size_t)grow * N + gcol] = f2bf(v);
        else
          ((float*)C)[(size_t)grow * N + gcol] = v;
      }
    }
  }
}

// H[node] = relu( (sum_{e in CSR[node]} XW_bf16[src(e)]) * isr_in[node] + b )
// 32 threads per node, 8 nodes/block. 4-wide unroll: 4 row loads in flight.
__global__ __launch_bounds__(256) void agg_kernel(
    const unsigned short* __restrict__ XW, const int* __restrict__ offs,
    const int* __restrict__ csr, const float* __restrict__ isr_in,
    const float* __restrict__ bias, float* __restrict__ H, int n) {
  int lane = threadIdx.x & 31;
  int node = blockIdx.x * 8 + (threadIdx.x >> 5);
  if (node >= n) return;
  int e0 = offs[node], e1 = offs[node + 1];
  float4 a0 = make_float4(0.f, 0.f, 0.f, 0.f);
  float4 a1 = a0, a2 = a0, a3 = a0;
  int e = e0;
  for (; e + 4 <= e1; e += 4) {
    int s0 = csr[e], s1 = csr[e + 1], s2 = csr[e + 2], s3 = csr[e + 3];
    ushort4 v0 = *reinterpret_cast<const ushort4*>(&XW[(size_t)s0 * 128 + lane * 4]);
    ushort4 v1 = *reinterpret_cast<const ushort4*>(&XW[(size_t)s1 * 128 + lane * 4]);
    ushort4 v2 = *reinterpret_cast<const ushort4*>(&XW[(size_t)s2 * 128 + lane * 4]);
    ushort4 v3 = *reinterpret_cast<const ushort4*>(&XW[(size_t)s3 * 128 + lane * 4]);
    a0.x += bf2f(v0.x); a0.y += bf2f(v0.y); a0.z += bf2f(v0.z); a0.w += bf2f(v0.w);
    a1.x += bf2f(v1.x); a1.y += bf2f(v1.y); a1.z += bf2f(v1.z); a1.w += bf2f(v1.w);
    a2.x += bf2f(v2.x); a2.y += bf2f(v2.y); a2.z += bf2f(v2.z); a2.w += bf2f(v2.w);
    a3.x += bf2f(v3.x); a3.y += bf2f(v3.y); a3.z += bf2f(v3.z); a3.w += bf2f(v3.w);
  }
  for (; e < e1; ++e) {
    int s = csr[e];
    ushort4 v = *reinterpret_cast<const ushort4*>(&XW[(size_t)s * 128 + lane * 4]);
    a0.x += bf2f(v.x); a0.y += bf2f(v.y); a0.z += bf2f(v.z); a0.w += bf2f(v.w);
  }
  float4 acc;
  acc.x = (a0.x + a1.x) + (a2.x + a3.x);
  acc.y = (a0.y + a1.y) + (a2.y + a3.y);
  acc.z = (a0.z + a1.z) + (a2.z + a3.z);
  acc.w = (a0.w + a1.w) + (a2.w + a3.w);
  float sc = isr_in[node];
  float4 b = *reinterpret_cast<const float4*>(&bias[lane * 4]);
  float4 o;
  o.x = fmaxf(fmaf(acc.x, sc, b.x), 0.f);
  o.y = fmaxf(fmaf(acc.y, sc, b.y), 0.f);
  o.z = fmaxf(fmaf(acc.z, sc, b.z), 0.f);
  o.w = fmaxf(fmaf(acc.w, sc, b.w), 0.f);
  *reinterpret_cast<float4*>(&H[(size_t)node * 128 + lane * 4]) = o;
}

// out[col] += column sums of X[n, ncol]; out pre-zeroed. ncol | 256.
__global__ __launch_bounds__(256) void colsum_kernel(const float* __restrict__ X,
                                                     float* __restrict__ out, int n, int ncol) {
  __shared__ float s[256];
  int col = threadIdx.x % ncol;
  int rpb = 256 / ncol;
  int rb = threadIdx.x / ncol;
  float acc = 0.f;
  for (int r = blockIdx.x * rpb + rb; r < n; r += gridDim.x * rpb)
    acc += X[(size_t)r * ncol + col];
  s[threadIdx.x] = acc;
  __syncthreads();
  if (threadIdx.x < ncol) {
    float v = 0.f;
    for (int i = 0; i < rpb; ++i) v += s[threadIdx.x + i * ncol];
    atomicAdd(&out[col], v);
  }
}

// out[col] = max over rows (X >= 0 relu output; out pre-zeroed).
__global__ __launch_bounds__(256) void colmax_kernel(const float* __restrict__ X,
                                                     unsigned* __restrict__ out, int n, int ncol) {
  __shared__ float s[256];
  int col = threadIdx.x % ncol;
  int rpb = 256 / ncol;
  int rb = threadIdx.x / ncol;
  float acc = 0.f;
  for (int r = blockIdx.x * rpb + rb; r < n; r += gridDim.x * rpb)
    acc = fmaxf(acc, X[(size_t)r * ncol + col]);
  s[threadIdx.x] = acc;
  __syncthreads();
  if (threadIdx.x < ncol) {
    float v = s[threadIdx.x];
    for (int i = 1; i < rpb; ++i) v = fmaxf(v, s[threadIdx.x + i * ncol]);
    atomicMax(&out[col], __float_as_uint(v));
  }
}

// norm_embed(a) + norm_embed(f) then @ W_cls + b_cls. Single block of 128.
__global__ __launch_bounds__(128) void final_kernel(
    const float* __restrict__ emb_a_sum, const unsigned* __restrict__ emb_f_bits,
    const float* __restrict__ W_cls, const float* __restrict__ b_cls,
    float* __restrict__ out, float inv_n_apig, int ncls) {
  __shared__ float red[128];
  __shared__ float emb[128];
  int t = threadIdx.x;
  float a = emb_a_sum[t] * inv_n_apig;
  float f = __uint_as_float(emb_f_bits[t]);

  float vals[2] = {a, f};
  float norms[2];
#pragma unroll
  for (int which = 0; which < 2; ++which) {
    float x = vals[which];
    red[t] = x;
    __syncthreads();
    for (int o = 64; o > 0; o >>= 1) {
      if (t < o) red[t] += red[t + o];
      __syncthreads();
    }
    float mean = red[0] / 128.f;
    __syncthreads();
    float d = x - mean;
    red[t] = d * d;
    __syncthreads();
    for (int o = 64; o > 0; o >>= 1) {
      if (t < o) red[t] += red[t + o];
      __syncthreads();
    }
    float stdv = sqrtf(red[0] / 127.f);  // ddof=1
    __syncthreads();
    float z = d / stdv;
    red[t] = z;
    __syncthreads();
    for (int o = 64; o > 0; o >>= 1) {
      if (t < o) red[t] = fminf(red[t], red[t + o]);
      __syncthreads();
    }
    float zmin = red[0];
    __syncthreads();
    red[t] = z;
    __syncthreads();
    for (int o = 64; o > 0; o >>= 1) {
      if (t < o) red[t] = fmaxf(red[t], red[t + o]);
      __syncthreads();
    }
    float zmax = red[0];
    __syncthreads();
    norms[which] = (z - zmin) / (zmax - zmin);
  }

  emb[t] = norms[0] + norms[1];
  __syncthreads();
  if (t < ncls) {
    float acc = b_cls[t];
    for (int k = 0; k < 128; ++k) acc = fmaf(emb[k], W_cls[k * ncls + t], acc);
    out[t] = acc;
  }
}

extern "C" void kernel_launch(void* const* d_in, const int* in_sizes, int n_in,
                              void* d_out, int out_size, void* d_ws, size_t ws_size,
                              hipStream_t stream) {
  const float* apig_feat = (const float*)d_in[0];
  const float* fcg_feat = (const float*)d_in[1];
  const float* W_a1 = (const float*)d_in[2];
  const float* b_a1 = (const float*)d_in[3];
  const float* W_a2 = (const float*)d_in[4];
  const float* b_a2 = (const float*)d_in[5];
  const float* W_f1 = (const float*)d_in[6];
  const float* b_f1 = (const float*)d_in[7];
  const float* W_f2 = (const float*)d_in[8];
  const float* b_f2 = (const float*)d_in[9];
  const float* W1 = (const float*)d_in[10];
  const float* b1 = (const float*)d_in[11];
  const float* W2 = (const float*)d_in[12];
  const float* b2 = (const float*)d_in[13];
  // d_in[14]/d_in[15] (W_attn, b_attn): dead — softmax over length-1 axis == 1.
  const float* W_cls = (const float*)d_in[16];
  const float* b_cls = (const float*)d_in[17];
  const int* a_src = (const int*)d_in[18];
  const int* a_dst = (const int*)d_in[19];
  const int* f_src = (const int*)d_in[20];
  const int* f_dst = (const int*)d_in[21];

  const int hidden = in_sizes[3];             // 128
  const int united = in_sizes[11];            // 64
  const int ncls = in_sizes[17];              // 10
  const int apig_dim = in_sizes[2] / hidden;  // 256
  const int fcg_dim = in_sizes[6] / hidden;   // 128
  const int n_a = in_sizes[0] / apig_dim;     // 50000
  const int n_f = in_sizes[1] / fcg_dim;      // 100000
  const int e_a = in_sizes[18];               // 800000
  const int e_f = in_sizes[20];               // 1600000

  // ---- workspace carve-up (all 256B aligned) ----
  char* w = (char*)d_ws;
  auto alloc = [&](size_t bytes) -> void* {
    void* p = (void*)w;
    w += (bytes + 255) & ~(size_t)255;
    return p;
  };
  float* isr_out_a = (float*)alloc((size_t)n_a * 4);
  float* isr_in_a = (float*)alloc((size_t)n_a * 4);
  float* isr_out_f = (float*)alloc((size_t)n_f * 4);
  float* isr_in_f = (float*)alloc((size_t)n_f * 4);
  int* cnt_out_a = (int*)alloc((size_t)n_a * 4);
  int* cnt_in_a = (int*)alloc((size_t)n_a * 4);
  int* offs_a = (int*)alloc((size_t)(n_a + 1) * 4);
  int* rank_a = (int*)alloc((size_t)e_a * 4);
  int* csr_a = (int*)alloc((size_t)e_a * 4);
  int* cnt_out_f = (int*)alloc((size_t)n_f * 4);
  int* cnt_in_f = (int*)alloc((size_t)n_f * 4);
  int* offs_f = (int*)alloc((size_t)(n_f + 1) * 4);
  int* rank_f = (int*)alloc((size_t)e_f * 4);
  int* csr_f = (int*)alloc((size_t)e_f * 4);
  int* blksum = (int*)alloc((size_t)128 * 4);
  unsigned short* G_a = (unsigned short*)alloc((size_t)n_a * hidden * 2);  // bf16 gather table
  float* H_a = (float*)alloc((size_t)n_a * hidden * 4);                    // h1 / a_dec / h2
  float* E_a = (float*)alloc((size_t)n_a * united * 4);                    // enc raw
  unsigned short* G_f = (unsigned short*)alloc((size_t)n_f * hidden * 2);
  float* H_f = (float*)alloc((size_t)n_f * hidden * 4);
  float* E_f = (float*)alloc((size_t)n_f * united * 4);
  float* a_sum = (float*)alloc((size_t)united * 4);
  float* f_sum = (float*)alloc((size_t)united * 4);
  float* emb_a = (float*)alloc((size_t)hidden * 4);
  unsigned* emb_f = (unsigned*)alloc((size_t)hidden * 4);
  (void)ws_size;
  (void)n_in;
  (void)out_size;

  const int Ba = (n_a + 4095) / 4096;
  const int Bf = (n_f + 4095) / 4096;
  const int E_tot = e_a + e_f;

  dim3 blk(256);

  // ---- zero counters/accumulators (1 dispatch) ----
  zero_kernel<<<(n_f + 255) / 256, blk, 0, stream>>>(
      cnt_out_a, cnt_in_a, n_a, cnt_out_f, cnt_in_f, n_f,
      a_sum, f_sum, united, emb_a, emb_f, hidden);

  // ---- degrees + rank + CSR (both graphs per dispatch) ----
  count2_kernel<<<(E_tot + 255) / 256, blk, 0, stream>>>(
      a_src, a_dst, cnt_out_a, cnt_in_a, rank_a, e_a,
      f_src, f_dst, cnt_out_f, cnt_in_f, rank_f, e_f);
  isr4_kernel<<<(n_f + 255) / 256, blk, 0, stream>>>(
      cnt_out_a, cnt_in_a, isr_out_a, isr_in_a, n_a,
      cnt_out_f, cnt_in_f, isr_out_f, isr_in_f, n_f);
  blocksum2_kernel<<<Ba + Bf, blk, 0, stream>>>(cnt_in_a, n_a, cnt_in_f, n_f, blksum, Ba);
  blkscan2_kernel<<<1, 64, 0, stream>>>(blksum, Ba, Bf);
  offsets2_kernel<<<Ba + Bf, blk, 0, stream>>>(cnt_in_a, offs_a, n_a, cnt_in_f, offs_f, n_f,
                                               blksum, Ba);
  scatter2_kernel<<<(E_tot + 255) / 256, blk, 0, stream>>>(
      a_src, a_dst, offs_a, rank_a, csr_a, e_a,
      f_src, f_dst, offs_f, rank_f, csr_f, e_f);

  const int ga = (n_a + 63) / 64, gf = (n_f + 63) / 64;

  // ---- apig conv1 + enc ----
  gemm_mfma_kernel<<<dim3(ga, hidden / 64), blk, 0, stream>>>(
      apig_feat, W_a1, G_a, n_a, hidden, apig_dim, nullptr, 0.f, isr_out_a, nullptr, 1);
  agg_kernel<<<(n_a + 7) / 8, blk, 0, stream>>>(G_a, offs_a, csr_a, isr_in_a, b_a1, H_a, n_a);
  gemm_mfma_kernel<<<dim3(ga, united / 64), blk, 0, stream>>>(
      H_a, W1, E_a, n_a, united, hidden, nullptr, 0.f, nullptr, b1, 0);
  colsum_kernel<<<256, blk, 0, stream>>>(E_a, a_sum, n_a, united);

  // ---- fcg conv1 + enc ----
  gemm_mfma_kernel<<<dim3(gf, hidden / 64), blk, 0, stream>>>(
      fcg_feat, W_f1, G_f, n_f, hidden, fcg_dim, nullptr, 0.f, isr_out_f, nullptr, 1);
  agg_kernel<<<(n_f + 7) / 8, blk, 0, stream>>>(G_f, offs_f, csr_f, isr_in_f, b_f1, H_f, n_f);
  gemm_mfma_kernel<<<dim3(gf, united / 64), blk, 0, stream>>>(
      H_f, W1, E_f, n_f, united, hidden, nullptr, 0.f, nullptr, b1, 0);
  colsum_kernel<<<256, blk, 0, stream>>>(E_f, f_sum, n_f, united);

  // ---- apig dec + conv2 + mean ----
  gemm_mfma_kernel<<<dim3(ga, hidden / 64), blk, 0, stream>>>(
      E_a, W2, H_a, n_a, hidden, united, f_sum, 0.1f, nullptr, b2, 0);  // a_dec
  gemm_mfma_kernel<<<dim3(ga, hidden / 64), blk, 0, stream>>>(
      H_a, W_a2, G_a, n_a, hidden, hidden, nullptr, 0.f, isr_out_a, nullptr, 1);
  agg_kernel<<<(n_a + 7) / 8, blk, 0, stream>>>(G_a, offs_a, csr_a, isr_in_a, b_a2, H_a, n_a);
  colsum_kernel<<<256, blk, 0, stream>>>(H_a, emb_a, n_a, hidden);

  // ---- fcg dec + conv2 + max ----
  gemm_mfma_kernel<<<dim3(gf, hidden / 64), blk, 0, stream>>>(
      E_f, W2, H_f, n_f, hidden, united, a_sum, 0.1f, nullptr, b2, 0);  // f_dec
  gemm_mfma_kernel<<<dim3(gf, hidden / 64), blk, 0, stream>>>(
      H_f, W_f2, G_f, n_f, hidden, hidden, nullptr, 0.f, isr_out_f, nullptr, 1);
  agg_kernel<<<(n_f + 7) / 8, blk, 0, stream>>>(G_f, offs_f, csr_f, isr_in_f, b_f2, H_f, n_f);
  colmax_kernel<<<256, blk, 0, stream>>>(H_f, emb_f, n_f, hidden);

  // ---- head ----
  final_kernel<<<1, 128, 0, stream>>>(emb_a, emb_f, W_cls, b_cls, (float*)d_out,
                                      1.0f / (float)n_a, ncls);
}